// Round 3
// baseline (1493.264 us; speedup 1.0000x reference)
//
#include <hip/hip_runtime.h>
#include <hip/hip_bf16.h>
#include <stdint.h>
#include <math.h>

// Problem constants
#define B_  32
#define N_  512
#define G_  512
#define D_  512
#define H_  16
#define KD_ 32

using bf16x8 = __attribute__((ext_vector_type(8))) short;
using f32x4  = __attribute__((ext_vector_type(4))) float;
typedef unsigned short u16;

__device__ __forceinline__ u16 f2b(float x) {
  union { __hip_bfloat16 h; u16 u; } c;
  c.h = __float2bfloat16(x);
  return c.u;
}
__device__ __forceinline__ float b2f(u16 u) {
  union { float f; unsigned int i; } c;
  c.i = ((unsigned int)u) << 16;
  return c.f;
}

// async global->LDS, 16B per lane. LDS dest is wave-uniform base; HW adds lane*16.
__device__ __forceinline__ void async16(void* lds, const void* g) {
  __builtin_amdgcn_global_load_lds(
      (const __attribute__((address_space(1))) unsigned int*)(uintptr_t)g,
      (__attribute__((address_space(3))) unsigned int*)(uintptr_t)lds,
      16, 0, 0);
}

// ---------------------------------------------------------------------------
// mean partials fused with hi/lo split of encoded_nodes. grid (32,8), block 512.
__global__ __launch_bounds__(512) void mean_split_kernel(
    const float* __restrict__ enc, u16* __restrict__ hi, u16* __restrict__ lo,
    float* __restrict__ partial)
{
  const int b  = blockIdx.x;
  const int nc = blockIdx.y;       // 8 chunks of 64 n
  const int d  = threadIdx.x;      // 512
  const size_t base = ((size_t)b * N_ + (size_t)nc * 64) * D_ + d;
  float psum = 0.f;
  for (int i = 0; i < 64; ++i) {
    float v = enc[base + (size_t)i * D_];
    psum += v;
    u16 h = f2b(v);
    hi[base + (size_t)i * D_] = h;
    lo[base + (size_t)i * D_] = f2b(v - b2f(h));
  }
  partial[((size_t)b * 8 + nc) * D_ + d] = psum;
}

// graph[b][d] = sum(partial)/512. grid 32, block 512.
__global__ __launch_bounds__(512) void mean_final_kernel(
    const float* __restrict__ partial, float* __restrict__ graph)
{
  const int b = blockIdx.x, d = threadIdx.x;
  float s = 0.f;
  for (int c = 0; c < 8; ++c) s += partial[((size_t)b * 8 + c) * D_ + d];
  graph[b * D_ + d] = s * (1.0f / N_);
}

// generic fp32 -> (hi,lo) bf16 split, 4 elems/thread
__global__ void split4_kernel(const float* __restrict__ in,
                              u16* __restrict__ hi, u16* __restrict__ lo, int n4)
{
  int i = blockIdx.x * blockDim.x + threadIdx.x;
  if (i < n4) {
    float4 v = ((const float4*)in)[i];
    ushort4 h, l;
    h.x = f2b(v.x); l.x = f2b(v.x - b2f(h.x));
    h.y = f2b(v.y); l.y = f2b(v.y - b2f(h.y));
    h.z = f2b(v.z); l.z = f2b(v.z - b2f(h.z));
    h.w = f2b(v.w); l.w = f2b(v.w - b2f(h.w));
    ((ushort4*)hi)[i] = h;
    ((ushort4*)lo)[i] = l;
  }
}

// (a+b) -> hi/lo split (for Wq_first + Wq_last)
__global__ void wsum_split_kernel(const float* __restrict__ a, const float* __restrict__ b,
                                  u16* __restrict__ hi, u16* __restrict__ lo, int n4)
{
  int i = blockIdx.x * blockDim.x + threadIdx.x;
  if (i < n4) {
    float4 va = ((const float4*)a)[i];
    float4 vb = ((const float4*)b)[i];
    float x0 = va.x + vb.x, x1 = va.y + vb.y, x2 = va.z + vb.z, x3 = va.w + vb.w;
    ushort4 h, l;
    h.x = f2b(x0); l.x = f2b(x0 - b2f(h.x));
    h.y = f2b(x1); l.y = f2b(x1 - b2f(h.y));
    h.z = f2b(x2); l.z = f2b(x2 - b2f(h.z));
    h.w = f2b(x3); l.w = f2b(x3 - b2f(h.w));
    ((ushort4*)hi)[i] = h;
    ((ushort4*)lo)[i] = l;
  }
}

// qg[b][d] = dot(graph[b][:], Wq_graph[d][:])  (tiny, fp32). grid (2,32), block 256
__global__ __launch_bounds__(256) void qg_kernel(
    const float* __restrict__ graph, const float* __restrict__ Wq,
    float* __restrict__ qg)
{
  const int b  = blockIdx.y;
  const int dd = blockIdx.x * 256 + threadIdx.x;
  const float* g = graph + b * D_;
  const float* w = Wq + (size_t)dd * D_;
  float s = 0.f;
  for (int k = 0; k < D_; ++k) s += g[k] * w[k];
  qg[b * D_ + dd] = s;
}

// ---------------------------------------------------------------------------
// C[M,N] = A[M,K] @ B[N,K]^T with split-precision bf16 (hi+lo pairs), fp32 accum.
// acc += Alo*Bhi + Ahi*Blo + Ahi*Bhi   (lo*lo dropped, ~2^-18)
// OUTMODE: 0 = fp32 single out (batched via sC), 1 = hi/lo bf16 row-major
// BIASMODE: 0 none, 1 +bias[(r>>9)*512 + c] (qg broadcast), 2 +bias[c] (bcomb)
// 128x128 tile, BK=32, 4 waves (2x2), wave tile 64x64. m97 structure.
template<int OUTMODE, int BIASMODE>
__global__ __launch_bounds__(256) void gemm_split_kernel(
    const u16* __restrict__ Ahi, const u16* __restrict__ Alo,
    const u16* __restrict__ Bhi, const u16* __restrict__ Blo,
    void* __restrict__ Chi, void* __restrict__ Clo,
    const float* __restrict__ bias,
    int M, int N, int K, long sA, long sB, long sC)
{
  __shared__ __align__(16) u16 AhS[4096], AlS[4096], BhS[4096], BlS[4096];

  const int z = blockIdx.z;
  Ahi += (size_t)z * sA; Alo += (size_t)z * sA;
  Bhi += (size_t)z * sB; Blo += (size_t)z * sB;

  const int brow = blockIdx.y * 128;
  const int bcol = blockIdx.x * 128;
  const int tid  = threadIdx.x;
  const int wid  = tid >> 6;
  const int lane = tid & 63;
  const int wr = wid >> 1, wc = wid & 1;

  f32x4 acc[4][4] = {};

  const int c0   = wid * 2;
  const int srow = lane >> 2;        // 0..15
  const int skk  = (lane & 3) * 8;   // 0,8,16,24

  const size_t g0 = (size_t)(brow + c0 * 16      + srow) * K + skk;
  const size_t g1 = (size_t)(brow + c0 * 16 + 16 + srow) * K + skk;
  const size_t h0 = (size_t)(bcol + c0 * 16      + srow) * K + skk;
  const size_t h1 = (size_t)(bcol + c0 * 16 + 16 + srow) * K + skk;
  u16* lA0 = &AhS[c0 * 512]; u16* lA1 = &AhS[c0 * 512 + 512];
  u16* la0 = &AlS[c0 * 512]; u16* la1 = &AlS[c0 * 512 + 512];
  u16* lB0 = &BhS[c0 * 512]; u16* lB1 = &BhS[c0 * 512 + 512];
  u16* lb0 = &BlS[c0 * 512]; u16* lb1 = &BlS[c0 * 512 + 512];

  const int aoff = (wr * 64 + (lane & 15)) * 32 + (lane >> 4) * 8;
  const int boff = (wc * 64 + (lane & 15)) * 32 + (lane >> 4) * 8;

  for (int k0 = 0; k0 < K; k0 += 32) {
    async16(lA0, Ahi + g0 + k0);
    async16(lA1, Ahi + g1 + k0);
    async16(la0, Alo + g0 + k0);
    async16(la1, Alo + g1 + k0);
    async16(lB0, Bhi + h0 + k0);
    async16(lB1, Bhi + h1 + k0);
    async16(lb0, Blo + h0 + k0);
    async16(lb1, Blo + h1 + k0);
    __syncthreads();   // drains vmcnt(0) before barrier

    bf16x8 ah[4], al[4], bh[4], bl[4];
#pragma unroll
    for (int m = 0; m < 4; ++m) {
      ah[m] = *(const bf16x8*)&AhS[aoff + m * 512];
      al[m] = *(const bf16x8*)&AlS[aoff + m * 512];
    }
#pragma unroll
    for (int n = 0; n < 4; ++n) {
      bh[n] = *(const bf16x8*)&BhS[boff + n * 512];
      bl[n] = *(const bf16x8*)&BlS[boff + n * 512];
    }
#pragma unroll
    for (int m = 0; m < 4; ++m)
#pragma unroll
      for (int n = 0; n < 4; ++n) {
        f32x4 t = acc[m][n];
        t = __builtin_amdgcn_mfma_f32_16x16x32_bf16(al[m], bh[n], t, 0, 0, 0);
        t = __builtin_amdgcn_mfma_f32_16x16x32_bf16(ah[m], bl[n], t, 0, 0, 0);
        t = __builtin_amdgcn_mfma_f32_16x16x32_bf16(ah[m], bh[n], t, 0, 0, 0);
        acc[m][n] = t;
      }
    __syncthreads();   // protect LDS before next stage overwrites
  }

  // epilogue. C/D layout: col = lane&15, row = (lane>>4)*4 + reg
  const int r0 = brow + wr * 64 + (lane >> 4) * 4;
  const int cbase = bcol + wc * 64 + (lane & 15);
#pragma unroll
  for (int m = 0; m < 4; ++m) {
#pragma unroll
    for (int n = 0; n < 4; ++n) {
      const int c = cbase + n * 16;
#pragma unroll
      for (int j = 0; j < 4; ++j) {
        const int r = r0 + m * 16 + j;
        float v = acc[m][n][j];
        if (BIASMODE == 1) v += bias[(r >> 9) * 512 + c];
        if (BIASMODE == 2) v += bias[c];
        if (OUTMODE == 0) {
          ((float*)Chi)[(size_t)z * sC + (size_t)r * N + c] = v;
        } else {
          u16 h = f2b(v);
          ((u16*)Chi)[(size_t)r * N + c] = h;
          ((u16*)Clo)[(size_t)r * N + c] = f2b(v - b2f(h));
        }
      }
    }
  }
}

// ---------------------------------------------------------------------------
// TRIANGULATION: simple, correctness-first stage-1 attention.
// One block (256 thr) per (b,h). K,V staged in LDS as fp32 (hi+lo reconstructed),
// straight (non-online) softmax per q-row, plain VALU dot products.
// grid: 512 = b*16 + h
__global__ __launch_bounds__(256) void attn_simple_kernel(
    const u16* __restrict__ Qhi, const u16* __restrict__ Qlo,
    const u16* __restrict__ Khi, const u16* __restrict__ Klo,
    const u16* __restrict__ Vhi, const u16* __restrict__ Vlo,
    const float* __restrict__ mask,
    u16* __restrict__ Ohi, u16* __restrict__ Olo)
{
  __shared__ float Kl[512][33];   // [n][kd], +1 pad
  __shared__ float Vl[512][33];   // [n][d],  +1 pad
  __shared__ float wbuf[4][512];

  const int tid = threadIdx.x, wid = tid >> 6, lane = tid & 63;
  const int h = blockIdx.x & 15, b = blockIdx.x >> 4;

  for (int j = tid; j < 512 * 32; j += 256) {
    const int n = j >> 5, d = j & 31;
    const size_t gi = ((size_t)b * N_ + n) * D_ + h * KD_ + d;
    Kl[n][d] = b2f(Khi[gi]) + b2f(Klo[gi]);
    Vl[n][d] = b2f(Vhi[gi]) + b2f(Vlo[gi]);
  }
  __syncthreads();

  const float scale = 0.17677669529663687f;  // 1/sqrt(32)

  for (int g = wid; g < G_; g += 4) {
    const size_t qi = ((size_t)b * G_ + g) * D_ + h * KD_;
    const float qv = b2f(Qhi[qi + (lane & 31)]) + b2f(Qlo[qi + (lane & 31)]);

    float sc[8] = {0.f, 0.f, 0.f, 0.f, 0.f, 0.f, 0.f, 0.f};
    for (int kd = 0; kd < 32; ++kd) {
      const float qk = __shfl(qv, kd);
#pragma unroll
      for (int t = 0; t < 8; ++t) sc[t] += qk * Kl[lane + 64 * t][kd];
    }

    const float* mrow = mask + ((size_t)b * G_ + g) * N_;
    float mx = -INFINITY;
#pragma unroll
    for (int t = 0; t < 8; ++t) {
      sc[t] = sc[t] * scale + mrow[lane + 64 * t];
      mx = fmaxf(mx, sc[t]);
    }
#pragma unroll
    for (int w = 1; w < 64; w <<= 1) mx = fmaxf(mx, __shfl_xor(mx, w));
    float sum = 0.f;
#pragma unroll
    for (int t = 0; t < 8; ++t) { sc[t] = __expf(sc[t] - mx); sum += sc[t]; }
#pragma unroll
    for (int w = 1; w < 64; w <<= 1) sum += __shfl_xor(sum, w);
#pragma unroll
    for (int t = 0; t < 8; ++t) wbuf[wid][lane + 64 * t] = sc[t];
    asm volatile("s_waitcnt lgkmcnt(0)" ::: "memory");

    const int d = lane & 31, half = lane >> 5;
    float acc = 0.f;
    const int nb = half * 256;
    for (int n = nb; n < nb + 256; ++n) acc += wbuf[wid][n] * Vl[n][d];
    acc += __shfl_xor(acc, 32);

    if (lane < 32) {
      const float v = acc / sum;
      const u16 hh = f2b(v);
      Ohi[qi + d] = hh;
      Olo[qi + d] = f2b(v - b2f(hh));
    }
  }
}

// ---------------------------------------------------------------------------
// Stage-2: s = 10*tanh(raw/sqrt(512)) + mask; softmax over n. In-place on d_out.
__global__ __launch_bounds__(256) void softmax2_kernel(
    float* __restrict__ S, const float* __restrict__ mask)
{
  const int row  = blockIdx.x * 4 + (threadIdx.x >> 6);
  const int lane = threadIdx.x & 63;
  float* r = S + (size_t)row * N_;
  const float* mk = mask + (size_t)row * N_;
  const float iscale = 0.04419417382415922f;  // 1/sqrt(512)

  float4 a  = *(const float4*)&r[lane * 8];
  float4 b4 = *(const float4*)&r[lane * 8 + 4];
  float4 ma = *(const float4*)&mk[lane * 8];
  float4 mb = *(const float4*)&mk[lane * 8 + 4];

  float v[8] = {a.x, a.y, a.z, a.w, b4.x, b4.y, b4.z, b4.w};
  float m[8] = {ma.x, ma.y, ma.z, ma.w, mb.x, mb.y, mb.z, mb.w};

#pragma unroll
  for (int i = 0; i < 8; ++i) {
    float x  = v[i] * iscale;
    float e2 = __expf(2.f * x);
    float t  = 1.f - 2.f / (e2 + 1.f);
    v[i] = 10.f * t + m[i];
  }
  float mx = v[0];
#pragma unroll
  for (int i = 1; i < 8; ++i) mx = fmaxf(mx, v[i]);
#pragma unroll
  for (int w = 1; w < 64; w <<= 1) mx = fmaxf(mx, __shfl_xor(mx, w));
  float sum = 0.f;
#pragma unroll
  for (int i = 0; i < 8; ++i) { v[i] = __expf(v[i] - mx); sum += v[i]; }
#pragma unroll
  for (int w = 1; w < 64; w <<= 1) sum += __shfl_xor(sum, w);
  const float inv = 1.f / sum;

  float4 oa = {v[0] * inv, v[1] * inv, v[2] * inv, v[3] * inv};
  float4 ob = {v[4] * inv, v[5] * inv, v[6] * inv, v[7] * inv};
  *(float4*)&r[lane * 8]     = oa;
  *(float4*)&r[lane * 8 + 4] = ob;
}

// ---------------------------------------------------------------------------
extern "C" void kernel_launch(void* const* d_in, const int* in_sizes, int n_in,
                              void* d_out, int out_size, void* d_ws, size_t ws_size,
                              hipStream_t stream)
{
  const float* enc_nodes = (const float*)d_in[0];
  const float* enc_last  = (const float*)d_in[1];
  const float* mask      = (const float*)d_in[2];
  const float* Wq_graph  = (const float*)d_in[3];
  const float* Wq_first  = (const float*)d_in[4];
  const float* Wq_last   = (const float*)d_in[5];
  const float* Wk        = (const float*)d_in[6];
  const float* Wv        = (const float*)d_in[7];
  const float* Wcomb     = (const float*)d_in[8];
  const float* bcomb     = (const float*)d_in[9];
  float* out = (float*)d_out;

  char* ws = (char*)d_ws;
  size_t off = 0;
  auto alloc = [&](size_t bytes) {
    void* p = ws + off;
    off += (bytes + 255) & ~(size_t)255;
    return p;
  };

  const size_t EL = (size_t)B_ * G_ * D_;  // 8388608
  u16* encNhi = (u16*)alloc(EL * 2);
  u16* encNlo = (u16*)alloc(EL * 2);
  u16* encLhi = (u16*)alloc(EL * 2);   // -> reused as attn_out hi
  u16* encLlo = (u16*)alloc(EL * 2);   // -> reused as attn_out lo
  u16* qhi    = (u16*)alloc(EL * 2);
  u16* qlo    = (u16*)alloc(EL * 2);
  u16* khi    = (u16*)alloc(EL * 2);   // -> reused as mh hi
  u16* klo    = (u16*)alloc(EL * 2);   // -> reused as mh lo
  u16* vhi    = (u16*)alloc(EL * 2);
  u16* vlo    = (u16*)alloc(EL * 2);
  u16* Wqlhi  = (u16*)alloc((size_t)D_ * D_ * 2);
  u16* Wqllo  = (u16*)alloc((size_t)D_ * D_ * 2);
  u16* Wkhi   = (u16*)alloc((size_t)D_ * D_ * 2);
  u16* Wklo   = (u16*)alloc((size_t)D_ * D_ * 2);
  u16* Wvhi   = (u16*)alloc((size_t)D_ * D_ * 2);
  u16* Wvlo   = (u16*)alloc((size_t)D_ * D_ * 2);
  u16* Wchi   = (u16*)alloc((size_t)D_ * D_ * 2);
  u16* Wclo   = (u16*)alloc((size_t)D_ * D_ * 2);
  float* partial = (float*)alloc((size_t)B_ * 8 * D_ * 4);
  float* graph   = (float*)alloc((size_t)B_ * D_ * 4);
  float* qg      = (float*)alloc((size_t)B_ * D_ * 4);
  u16* athi = encLhi; u16* atlo = encLlo;  // encL dead after q GEMM
  u16* mhhi = khi;    u16* mhlo = klo;     // k dead after attention

  mean_split_kernel<<<dim3(32, 8), 512, 0, stream>>>(enc_nodes, encNhi, encNlo, partial);
  mean_final_kernel<<<dim3(32), 512, 0, stream>>>(partial, graph);
  split4_kernel<<<dim3(8192), 256, 0, stream>>>(enc_last, encLhi, encLlo, (int)(EL / 4));
  wsum_split_kernel<<<dim3(256), 256, 0, stream>>>(Wq_first, Wq_last, Wqlhi, Wqllo, 65536);
  split4_kernel<<<dim3(256), 256, 0, stream>>>(Wk, Wkhi, Wklo, 65536);
  split4_kernel<<<dim3(256), 256, 0, stream>>>(Wv, Wvhi, Wvlo, 65536);
  split4_kernel<<<dim3(256), 256, 0, stream>>>(Wcomb, Wchi, Wclo, 65536);
  qg_kernel<<<dim3(2, 32), 256, 0, stream>>>(graph, Wq_graph, qg);

  // q = encL @ (Wq_first+Wq_last)^T + qg[b]
  gemm_split_kernel<1, 1><<<dim3(4, 128, 1), 256, 0, stream>>>(
      encLhi, encLlo, Wqlhi, Wqllo, qhi, qlo, qg, 16384, 512, 512, 0, 0, 0);
  // k = encN @ Wk^T
  gemm_split_kernel<1, 0><<<dim3(4, 128, 1), 256, 0, stream>>>(
      encNhi, encNlo, Wkhi, Wklo, khi, klo, nullptr, 16384, 512, 512, 0, 0, 0);
  // v = encN @ Wv^T (row-major this round; VT path removed for triangulation)
  gemm_split_kernel<1, 0><<<dim3(4, 128, 1), 256, 0, stream>>>(
      encNhi, encNlo, Wvhi, Wvlo, vhi, vlo, nullptr, 16384, 512, 512, 0, 0, 0);

  attn_simple_kernel<<<dim3(512), 256, 0, stream>>>(
      qhi, qlo, khi, klo, vhi, vlo, mask, athi, atlo);

  // mh = attn_out @ Wcomb^T + bcomb
  gemm_split_kernel<1, 2><<<dim3(4, 128, 1), 256, 0, stream>>>(
      athi, atlo, Wchi, Wclo, mhhi, mhlo, bcomb, 16384, 512, 512, 0, 0, 0);
  // s2 raw = mh[b] @ encN[b]^T -> fp32 into d_out (batched over b)
  gemm_split_kernel<0, 0><<<dim3(4, 4, 32), 256, 0, stream>>>(
      mhhi, mhlo, encNhi, encNlo, out, nullptr, nullptr, 512, 512, 512,
      262144, 262144, 262144);

  softmax2_kernel<<<dim3(4096), 256, 0, stream>>>(out, mask);
}

// Round 4
// 586.145 us; speedup vs baseline: 2.5476x; 2.5476x over previous
//
#include <hip/hip_runtime.h>
#include <hip/hip_bf16.h>
#include <stdint.h>
#include <math.h>

// Problem constants
#define B_  32
#define N_  512
#define G_  512
#define D_  512
#define H_  16
#define KD_ 32

using bf16x8 = __attribute__((ext_vector_type(8))) short;
using f32x4  = __attribute__((ext_vector_type(4))) float;
typedef unsigned short u16;

__device__ __forceinline__ u16 f2b(float x) {
  union { __hip_bfloat16 h; u16 u; } c;
  c.h = __float2bfloat16(x);
  return c.u;
}
__device__ __forceinline__ float b2f(u16 u) {
  union { float f; unsigned int i; } c;
  c.i = ((unsigned int)u) << 16;
  return c.f;
}

// async global->LDS, 16B per lane. LDS dest is wave-uniform base; HW adds lane*16.
__device__ __forceinline__ void async16(void* lds, const void* g) {
  __builtin_amdgcn_global_load_lds(
      (const __attribute__((address_space(1))) unsigned int*)(uintptr_t)g,
      (__attribute__((address_space(3))) unsigned int*)(uintptr_t)lds,
      16, 0, 0);
}

// ---------------------------------------------------------------------------
// mean partials fused with hi/lo split of encoded_nodes. grid (32,8), block 512.
__global__ __launch_bounds__(512) void mean_split_kernel(
    const float* __restrict__ enc, u16* __restrict__ hi, u16* __restrict__ lo,
    float* __restrict__ partial)
{
  const int b  = blockIdx.x;
  const int nc = blockIdx.y;       // 8 chunks of 64 n
  const int d  = threadIdx.x;      // 512
  const size_t base = ((size_t)b * N_ + (size_t)nc * 64) * D_ + d;
  float psum = 0.f;
  for (int i = 0; i < 64; ++i) {
    float v = enc[base + (size_t)i * D_];
    psum += v;
    u16 h = f2b(v);
    hi[base + (size_t)i * D_] = h;
    lo[base + (size_t)i * D_] = f2b(v - b2f(h));
  }
  partial[((size_t)b * 8 + nc) * D_ + d] = psum;
}

// graph[b][d] = sum(partial)/512. grid 32, block 512.
__global__ __launch_bounds__(512) void mean_final_kernel(
    const float* __restrict__ partial, float* __restrict__ graph)
{
  const int b = blockIdx.x, d = threadIdx.x;
  float s = 0.f;
  for (int c = 0; c < 8; ++c) s += partial[((size_t)b * 8 + c) * D_ + d];
  graph[b * D_ + d] = s * (1.0f / N_);
}

// generic fp32 -> (hi,lo) bf16 split, 4 elems/thread
__global__ void split4_kernel(const float* __restrict__ in,
                              u16* __restrict__ hi, u16* __restrict__ lo, int n4)
{
  int i = blockIdx.x * blockDim.x + threadIdx.x;
  if (i < n4) {
    float4 v = ((const float4*)in)[i];
    ushort4 h, l;
    h.x = f2b(v.x); l.x = f2b(v.x - b2f(h.x));
    h.y = f2b(v.y); l.y = f2b(v.y - b2f(h.y));
    h.z = f2b(v.z); l.z = f2b(v.z - b2f(h.z));
    h.w = f2b(v.w); l.w = f2b(v.w - b2f(h.w));
    ((ushort4*)hi)[i] = h;
    ((ushort4*)lo)[i] = l;
  }
}

// (a+b) -> hi/lo split (for Wq_first + Wq_last)
__global__ void wsum_split_kernel(const float* __restrict__ a, const float* __restrict__ b,
                                  u16* __restrict__ hi, u16* __restrict__ lo, int n4)
{
  int i = blockIdx.x * blockDim.x + threadIdx.x;
  if (i < n4) {
    float4 va = ((const float4*)a)[i];
    float4 vb = ((const float4*)b)[i];
    float x0 = va.x + vb.x, x1 = va.y + vb.y, x2 = va.z + vb.z, x3 = va.w + vb.w;
    ushort4 h, l;
    h.x = f2b(x0); l.x = f2b(x0 - b2f(h.x));
    h.y = f2b(x1); l.y = f2b(x1 - b2f(h.y));
    h.z = f2b(x2); l.z = f2b(x2 - b2f(h.z));
    h.w = f2b(x3); l.w = f2b(x3 - b2f(h.w));
    ((ushort4*)hi)[i] = h;
    ((ushort4*)lo)[i] = l;
  }
}

// qg[b][d] = dot(graph[b][:], Wq_graph[d][:])  (tiny, fp32). grid (2,32), block 256
__global__ __launch_bounds__(256) void qg_kernel(
    const float* __restrict__ graph, const float* __restrict__ Wq,
    float* __restrict__ qg)
{
  const int b  = blockIdx.y;
  const int dd = blockIdx.x * 256 + threadIdx.x;
  const float* g = graph + b * D_;
  const float* w = Wq + (size_t)dd * D_;
  float s = 0.f;
  for (int k = 0; k < D_; ++k) s += g[k] * w[k];
  qg[b * D_ + dd] = s;
}

// ---------------------------------------------------------------------------
// V transpose: VT[b][h][d][n] = V[b*512+n][h*32+d]. Trivially correct by
// construction. grid 512 = b*16+h, block 256.
__global__ __launch_bounds__(256) void vtrans_kernel(
    const u16* __restrict__ vhi, const u16* __restrict__ vlo,
    u16* __restrict__ vThi, u16* __restrict__ vTlo)
{
  const int b = blockIdx.x >> 4, h = blockIdx.x & 15;
  for (int d = 0; d < 32; ++d) {
#pragma unroll
    for (int c = 0; c < 2; ++c) {
      const int n = c * 256 + threadIdx.x;
      const size_t src = ((size_t)(b * 512 + n)) * 512 + h * 32 + d;
      const size_t dst = (((size_t)b * 16 + h) * 32 + d) * 512 + n;
      vThi[dst] = vhi[src];
      vTlo[dst] = vlo[src];
    }
  }
}

// ---------------------------------------------------------------------------
// C[M,N] = A[M,K] @ B[N,K]^T with split-precision bf16 (hi+lo pairs), fp32 accum.
// acc += Alo*Bhi + Ahi*Blo + Ahi*Bhi   (lo*lo dropped, ~2^-18)
// OUTMODE: 0 = fp32 single out (batched via sC), 1 = hi/lo bf16 row-major
// BIASMODE: 0 none, 1 +bias[(r>>9)*512 + c] (qg broadcast), 2 +bias[c] (bcomb)
// 128x128 tile, BK=32, 4 waves (2x2), wave tile 64x64. m97 structure.
template<int OUTMODE, int BIASMODE>
__global__ __launch_bounds__(256) void gemm_split_kernel(
    const u16* __restrict__ Ahi, const u16* __restrict__ Alo,
    const u16* __restrict__ Bhi, const u16* __restrict__ Blo,
    void* __restrict__ Chi, void* __restrict__ Clo,
    const float* __restrict__ bias,
    int M, int N, int K, long sA, long sB, long sC)
{
  __shared__ __align__(16) u16 AhS[4096], AlS[4096], BhS[4096], BlS[4096];

  const int z = blockIdx.z;
  Ahi += (size_t)z * sA; Alo += (size_t)z * sA;
  Bhi += (size_t)z * sB; Blo += (size_t)z * sB;

  const int brow = blockIdx.y * 128;
  const int bcol = blockIdx.x * 128;
  const int tid  = threadIdx.x;
  const int wid  = tid >> 6;
  const int lane = tid & 63;
  const int wr = wid >> 1, wc = wid & 1;

  f32x4 acc[4][4] = {};

  const int c0   = wid * 2;
  const int srow = lane >> 2;        // 0..15
  const int skk  = (lane & 3) * 8;   // 0,8,16,24

  const size_t g0 = (size_t)(brow + c0 * 16      + srow) * K + skk;
  const size_t g1 = (size_t)(brow + c0 * 16 + 16 + srow) * K + skk;
  const size_t h0 = (size_t)(bcol + c0 * 16      + srow) * K + skk;
  const size_t h1 = (size_t)(bcol + c0 * 16 + 16 + srow) * K + skk;
  u16* lA0 = &AhS[c0 * 512]; u16* lA1 = &AhS[c0 * 512 + 512];
  u16* la0 = &AlS[c0 * 512]; u16* la1 = &AlS[c0 * 512 + 512];
  u16* lB0 = &BhS[c0 * 512]; u16* lB1 = &BhS[c0 * 512 + 512];
  u16* lb0 = &BlS[c0 * 512]; u16* lb1 = &BlS[c0 * 512 + 512];

  const int aoff = (wr * 64 + (lane & 15)) * 32 + (lane >> 4) * 8;
  const int boff = (wc * 64 + (lane & 15)) * 32 + (lane >> 4) * 8;

  for (int k0 = 0; k0 < K; k0 += 32) {
    async16(lA0, Ahi + g0 + k0);
    async16(lA1, Ahi + g1 + k0);
    async16(la0, Alo + g0 + k0);
    async16(la1, Alo + g1 + k0);
    async16(lB0, Bhi + h0 + k0);
    async16(lB1, Bhi + h1 + k0);
    async16(lb0, Blo + h0 + k0);
    async16(lb1, Blo + h1 + k0);
    __syncthreads();   // drains vmcnt(0) before barrier

    bf16x8 ah[4], al[4], bh[4], bl[4];
#pragma unroll
    for (int m = 0; m < 4; ++m) {
      ah[m] = *(const bf16x8*)&AhS[aoff + m * 512];
      al[m] = *(const bf16x8*)&AlS[aoff + m * 512];
    }
#pragma unroll
    for (int n = 0; n < 4; ++n) {
      bh[n] = *(const bf16x8*)&BhS[boff + n * 512];
      bl[n] = *(const bf16x8*)&BlS[boff + n * 512];
    }
#pragma unroll
    for (int m = 0; m < 4; ++m)
#pragma unroll
      for (int n = 0; n < 4; ++n) {
        f32x4 t = acc[m][n];
        t = __builtin_amdgcn_mfma_f32_16x16x32_bf16(al[m], bh[n], t, 0, 0, 0);
        t = __builtin_amdgcn_mfma_f32_16x16x32_bf16(ah[m], bl[n], t, 0, 0, 0);
        t = __builtin_amdgcn_mfma_f32_16x16x32_bf16(ah[m], bh[n], t, 0, 0, 0);
        acc[m][n] = t;
      }
    __syncthreads();   // protect LDS before next stage overwrites
  }

  // epilogue. C/D layout: col = lane&15, row = (lane>>4)*4 + reg
  const int r0 = brow + wr * 64 + (lane >> 4) * 4;
  const int cbase = bcol + wc * 64 + (lane & 15);
#pragma unroll
  for (int m = 0; m < 4; ++m) {
#pragma unroll
    for (int n = 0; n < 4; ++n) {
      const int c = cbase + n * 16;
#pragma unroll
      for (int j = 0; j < 4; ++j) {
        const int r = r0 + m * 16 + j;
        float v = acc[m][n][j];
        if (BIASMODE == 1) v += bias[(r >> 9) * 512 + c];
        if (BIASMODE == 2) v += bias[c];
        if (OUTMODE == 0) {
          ((float*)Chi)[(size_t)z * sC + (size_t)r * N + c] = v;
        } else {
          u16 h = f2b(v);
          ((u16*)Chi)[(size_t)r * N + c] = h;
          ((u16*)Clo)[(size_t)r * N + c] = f2b(v - b2f(h));
        }
      }
    }
  }
}

// ---------------------------------------------------------------------------
// Stage-1 attention, MFMA, TWO-PASS softmax (exact row max; no online rescale).
// 1 wave = 32 q-rows of one (b,h); block = 4 waves = 128 q-rows.
// grid 2048 = ((b*4 + gblk)*16 + h), h fastest for mask L2 reuse.
__global__ __launch_bounds__(256) void attn_mfma_kernel(
    const u16* __restrict__ Qhi, const u16* __restrict__ Qlo,
    const u16* __restrict__ Khi, const u16* __restrict__ Klo,
    const u16* __restrict__ VThi, const u16* __restrict__ VTlo,
    const float* __restrict__ mask,
    u16* __restrict__ Ohi, u16* __restrict__ Olo)
{
  __shared__ __align__(16) u16 Ph[4][32][56], Pl[4][32][56];  // 112B row stride

  const int tid = threadIdx.x, wid = tid >> 6, lane = tid & 63;
  const int id   = blockIdx.x;
  const int h    = id & 15;
  const int gblk = (id >> 4) & 3;
  const int b    = id >> 6;
  const int g0   = gblk * 128 + wid * 32;
  const int colq = lane & 15, rowg = lane >> 4;

  const size_t qb = ((size_t)b * G_ + g0) * D_ + h * KD_;
  const size_t kb = ((size_t)b * N_) * D_ + h * KD_;
  const size_t vb = (((size_t)b * H_ + h) * KD_) * (size_t)N_;
  const float* Mb = mask + ((size_t)b * G_ + g0) * N_;

  bf16x8 qh[2], ql[2];
  qh[0] = *(const bf16x8*)&Qhi[qb + (size_t)colq * D_ + rowg * 8];
  ql[0] = *(const bf16x8*)&Qlo[qb + (size_t)colq * D_ + rowg * 8];
  qh[1] = *(const bf16x8*)&Qhi[qb + (size_t)(16 + colq) * D_ + rowg * 8];
  ql[1] = *(const bf16x8*)&Qlo[qb + (size_t)(16 + colq) * D_ + rowg * 8];

  const float scale = 0.17677669529663687f;  // 1/sqrt(32)
  const f32x4 zf = {0.f, 0.f, 0.f, 0.f};

  float mrow[2][4];
#pragma unroll
  for (int rf = 0; rf < 2; ++rf)
#pragma unroll
    for (int j = 0; j < 4; ++j) mrow[rf][j] = -3.0e38f;

  // ---- pass A: exact row maxima ----
  for (int n0 = 0; n0 < N_; n0 += 32) {
    bf16x8 kh0 = *(const bf16x8*)&Khi[kb + (size_t)(n0 + colq) * D_ + rowg * 8];
    bf16x8 kl0 = *(const bf16x8*)&Klo[kb + (size_t)(n0 + colq) * D_ + rowg * 8];
    bf16x8 kh1 = *(const bf16x8*)&Khi[kb + (size_t)(n0 + 16 + colq) * D_ + rowg * 8];
    bf16x8 kl1 = *(const bf16x8*)&Klo[kb + (size_t)(n0 + 16 + colq) * D_ + rowg * 8];
#pragma unroll
    for (int rf = 0; rf < 2; ++rf) {
      f32x4 t0 = __builtin_amdgcn_mfma_f32_16x16x32_bf16(ql[rf], kh0, zf, 0, 0, 0);
      t0 = __builtin_amdgcn_mfma_f32_16x16x32_bf16(qh[rf], kl0, t0, 0, 0, 0);
      t0 = __builtin_amdgcn_mfma_f32_16x16x32_bf16(qh[rf], kh0, t0, 0, 0, 0);
      f32x4 t1 = __builtin_amdgcn_mfma_f32_16x16x32_bf16(ql[rf], kh1, zf, 0, 0, 0);
      t1 = __builtin_amdgcn_mfma_f32_16x16x32_bf16(qh[rf], kl1, t1, 0, 0, 0);
      t1 = __builtin_amdgcn_mfma_f32_16x16x32_bf16(qh[rf], kh1, t1, 0, 0, 0);
#pragma unroll
      for (int j = 0; j < 4; ++j) {
        const int gg = rf * 16 + rowg * 4 + j;
        float v0 = t0[j] * scale + Mb[(size_t)gg * N_ + n0 + colq];
        float v1 = t1[j] * scale + Mb[(size_t)gg * N_ + n0 + 16 + colq];
        float cm = fmaxf(v0, v1);
#pragma unroll
        for (int w = 1; w < 16; w <<= 1) cm = fmaxf(cm, __shfl_xor(cm, w));
        mrow[rf][j] = fmaxf(mrow[rf][j], cm);
      }
    }
  }

  // ---- pass B: P = exp(s - max), denom, and P.V accumulation ----
  float lrow[2][4] = {};
  f32x4 o[2][2] = {};

  for (int n0 = 0; n0 < N_; n0 += 32) {
    bf16x8 kh0 = *(const bf16x8*)&Khi[kb + (size_t)(n0 + colq) * D_ + rowg * 8];
    bf16x8 kl0 = *(const bf16x8*)&Klo[kb + (size_t)(n0 + colq) * D_ + rowg * 8];
    bf16x8 kh1 = *(const bf16x8*)&Khi[kb + (size_t)(n0 + 16 + colq) * D_ + rowg * 8];
    bf16x8 kl1 = *(const bf16x8*)&Klo[kb + (size_t)(n0 + 16 + colq) * D_ + rowg * 8];
#pragma unroll
    for (int rf = 0; rf < 2; ++rf) {
      f32x4 t0 = __builtin_amdgcn_mfma_f32_16x16x32_bf16(ql[rf], kh0, zf, 0, 0, 0);
      t0 = __builtin_amdgcn_mfma_f32_16x16x32_bf16(qh[rf], kl0, t0, 0, 0, 0);
      t0 = __builtin_amdgcn_mfma_f32_16x16x32_bf16(qh[rf], kh0, t0, 0, 0, 0);
      f32x4 t1 = __builtin_amdgcn_mfma_f32_16x16x32_bf16(ql[rf], kh1, zf, 0, 0, 0);
      t1 = __builtin_amdgcn_mfma_f32_16x16x32_bf16(qh[rf], kl1, t1, 0, 0, 0);
      t1 = __builtin_amdgcn_mfma_f32_16x16x32_bf16(qh[rf], kh1, t1, 0, 0, 0);
#pragma unroll
      for (int j = 0; j < 4; ++j) {
        const int gg = rf * 16 + rowg * 4 + j;
        float v0 = t0[j] * scale + Mb[(size_t)gg * N_ + n0 + colq];
        float v1 = t1[j] * scale + Mb[(size_t)gg * N_ + n0 + 16 + colq];
        float p0 = __expf(v0 - mrow[rf][j]);
        float p1 = __expf(v1 - mrow[rf][j]);
        float rs = p0 + p1;
#pragma unroll
        for (int w = 1; w < 16; w <<= 1) rs += __shfl_xor(rs, w);
        lrow[rf][j] += rs;
        u16 h0 = f2b(p0), h1 = f2b(p1);
        Ph[wid][gg][colq]      = h0;
        Pl[wid][gg][colq]      = f2b(p0 - b2f(h0));
        Ph[wid][gg][16 + colq] = h1;
        Pl[wid][gg][16 + colq] = f2b(p1 - b2f(h1));
      }
    }
    __syncthreads();

    bf16x8 ph0 = *(const bf16x8*)&Ph[wid][colq][rowg * 8];
    bf16x8 pl0 = *(const bf16x8*)&Pl[wid][colq][rowg * 8];
    bf16x8 ph1 = *(const bf16x8*)&Ph[wid][16 + colq][rowg * 8];
    bf16x8 pl1 = *(const bf16x8*)&Pl[wid][16 + colq][rowg * 8];
    bf16x8 vh0 = *(const bf16x8*)&VThi[vb + (size_t)colq * N_ + n0 + rowg * 8];
    bf16x8 vl0 = *(const bf16x8*)&VTlo[vb + (size_t)colq * N_ + n0 + rowg * 8];
    bf16x8 vh1 = *(const bf16x8*)&VThi[vb + (size_t)(16 + colq) * N_ + n0 + rowg * 8];
    bf16x8 vl1 = *(const bf16x8*)&VTlo[vb + (size_t)(16 + colq) * N_ + n0 + rowg * 8];

    o[0][0] = __builtin_amdgcn_mfma_f32_16x16x32_bf16(pl0, vh0, o[0][0], 0, 0, 0);
    o[0][0] = __builtin_amdgcn_mfma_f32_16x16x32_bf16(ph0, vl0, o[0][0], 0, 0, 0);
    o[0][0] = __builtin_amdgcn_mfma_f32_16x16x32_bf16(ph0, vh0, o[0][0], 0, 0, 0);
    o[0][1] = __builtin_amdgcn_mfma_f32_16x16x32_bf16(pl0, vh1, o[0][1], 0, 0, 0);
    o[0][1] = __builtin_amdgcn_mfma_f32_16x16x32_bf16(ph0, vl1, o[0][1], 0, 0, 0);
    o[0][1] = __builtin_amdgcn_mfma_f32_16x16x32_bf16(ph0, vh1, o[0][1], 0, 0, 0);
    o[1][0] = __builtin_amdgcn_mfma_f32_16x16x32_bf16(pl1, vh0, o[1][0], 0, 0, 0);
    o[1][0] = __builtin_amdgcn_mfma_f32_16x16x32_bf16(ph1, vl0, o[1][0], 0, 0, 0);
    o[1][0] = __builtin_amdgcn_mfma_f32_16x16x32_bf16(ph1, vh0, o[1][0], 0, 0, 0);
    o[1][1] = __builtin_amdgcn_mfma_f32_16x16x32_bf16(pl1, vh1, o[1][1], 0, 0, 0);
    o[1][1] = __builtin_amdgcn_mfma_f32_16x16x32_bf16(ph1, vl1, o[1][1], 0, 0, 0);
    o[1][1] = __builtin_amdgcn_mfma_f32_16x16x32_bf16(ph1, vh1, o[1][1], 0, 0, 0);
    __syncthreads();
  }

#pragma unroll
  for (int rf = 0; rf < 2; ++rf)
#pragma unroll
    for (int j = 0; j < 4; ++j) {
      const float inv = 1.f / lrow[rf][j];
      const int gg = rf * 16 + rowg * 4 + j;
      float v0 = o[rf][0][j] * inv;
      float v1 = o[rf][1][j] * inv;
      u16 h0 = f2b(v0), h1 = f2b(v1);
      Ohi[qb + (size_t)gg * D_ + colq]      = h0;
      Olo[qb + (size_t)gg * D_ + colq]      = f2b(v0 - b2f(h0));
      Ohi[qb + (size_t)gg * D_ + 16 + colq] = h1;
      Olo[qb + (size_t)gg * D_ + 16 + colq] = f2b(v1 - b2f(h1));
    }
}

// ---------------------------------------------------------------------------
// Stage-2: s = 10*tanh(raw/sqrt(512)) + mask; softmax over n. In-place on d_out.
__global__ __launch_bounds__(256) void softmax2_kernel(
    float* __restrict__ S, const float* __restrict__ mask)
{
  const int row  = blockIdx.x * 4 + (threadIdx.x >> 6);
  const int lane = threadIdx.x & 63;
  float* r = S + (size_t)row * N_;
  const float* mk = mask + (size_t)row * N_;
  const float iscale = 0.04419417382415922f;  // 1/sqrt(512)

  float4 a  = *(const float4*)&r[lane * 8];
  float4 b4 = *(const float4*)&r[lane * 8 + 4];
  float4 ma = *(const float4*)&mk[lane * 8];
  float4 mb = *(const float4*)&mk[lane * 8 + 4];

  float v[8] = {a.x, a.y, a.z, a.w, b4.x, b4.y, b4.z, b4.w};
  float m[8] = {ma.x, ma.y, ma.z, ma.w, mb.x, mb.y, mb.z, mb.w};

#pragma unroll
  for (int i = 0; i < 8; ++i) {
    float x  = v[i] * iscale;
    float e2 = __expf(2.f * x);
    float t  = 1.f - 2.f / (e2 + 1.f);
    v[i] = 10.f * t + m[i];
  }
  float mx = v[0];
#pragma unroll
  for (int i = 1; i < 8; ++i) mx = fmaxf(mx, v[i]);
#pragma unroll
  for (int w = 1; w < 64; w <<= 1) mx = fmaxf(mx, __shfl_xor(mx, w));
  float sum = 0.f;
#pragma unroll
  for (int i = 0; i < 8; ++i) { v[i] = __expf(v[i] - mx); sum += v[i]; }
#pragma unroll
  for (int w = 1; w < 64; w <<= 1) sum += __shfl_xor(sum, w);
  const float inv = 1.f / sum;

  float4 oa = {v[0] * inv, v[1] * inv, v[2] * inv, v[3] * inv};
  float4 ob = {v[4] * inv, v[5] * inv, v[6] * inv, v[7] * inv};
  *(float4*)&r[lane * 8]     = oa;
  *(float4*)&r[lane * 8 + 4] = ob;
}

// ---------------------------------------------------------------------------
extern "C" void kernel_launch(void* const* d_in, const int* in_sizes, int n_in,
                              void* d_out, int out_size, void* d_ws, size_t ws_size,
                              hipStream_t stream)
{
  const float* enc_nodes = (const float*)d_in[0];
  const float* enc_last  = (const float*)d_in[1];
  const float* mask      = (const float*)d_in[2];
  const float* Wq_graph  = (const float*)d_in[3];
  const float* Wq_first  = (const float*)d_in[4];
  const float* Wq_last   = (const float*)d_in[5];
  const float* Wk        = (const float*)d_in[6];
  const float* Wv        = (const float*)d_in[7];
  const float* Wcomb     = (const float*)d_in[8];
  const float* bcomb     = (const float*)d_in[9];
  float* out = (float*)d_out;

  char* ws = (char*)d_ws;
  size_t off = 0;
  auto alloc = [&](size_t bytes) {
    void* p = ws + off;
    off += (bytes + 255) & ~(size_t)255;
    return p;
  };

  const size_t EL = (size_t)B_ * G_ * D_;  // 8388608
  u16* encNhi = (u16*)alloc(EL * 2);
  u16* encNlo = (u16*)alloc(EL * 2);
  u16* encLhi = (u16*)alloc(EL * 2);   // -> reused as VT hi after q GEMM
  u16* encLlo = (u16*)alloc(EL * 2);   // -> reused as VT lo
  u16* qhi    = (u16*)alloc(EL * 2);
  u16* qlo    = (u16*)alloc(EL * 2);
  u16* khi    = (u16*)alloc(EL * 2);   // -> reused as mh hi after attention
  u16* klo    = (u16*)alloc(EL * 2);   // -> reused as mh lo
  u16* vhi    = (u16*)alloc(EL * 2);   // row-major V -> reused as attn_out hi
  u16* vlo    = (u16*)alloc(EL * 2);   // -> reused as attn_out lo
  u16* Wqlhi  = (u16*)alloc((size_t)D_ * D_ * 2);
  u16* Wqllo  = (u16*)alloc((size_t)D_ * D_ * 2);
  u16* Wkhi   = (u16*)alloc((size_t)D_ * D_ * 2);
  u16* Wklo   = (u16*)alloc((size_t)D_ * D_ * 2);
  u16* Wvhi   = (u16*)alloc((size_t)D_ * D_ * 2);
  u16* Wvlo   = (u16*)alloc((size_t)D_ * D_ * 2);
  u16* Wchi   = (u16*)alloc((size_t)D_ * D_ * 2);
  u16* Wclo   = (u16*)alloc((size_t)D_ * D_ * 2);
  float* partial = (float*)alloc((size_t)B_ * 8 * D_ * 4);
  float* graph   = (float*)alloc((size_t)B_ * D_ * 4);
  float* qg      = (float*)alloc((size_t)B_ * D_ * 4);
  u16* vThi = encLhi; u16* vTlo = encLlo;  // encL dead after q GEMM
  u16* athi = vhi;    u16* atlo = vlo;     // row-major V dead after vtrans
  u16* mhhi = khi;    u16* mhlo = klo;     // k dead after attention

  mean_split_kernel<<<dim3(32, 8), 512, 0, stream>>>(enc_nodes, encNhi, encNlo, partial);
  mean_final_kernel<<<dim3(32), 512, 0, stream>>>(partial, graph);
  split4_kernel<<<dim3(8192), 256, 0, stream>>>(enc_last, encLhi, encLlo, (int)(EL / 4));
  wsum_split_kernel<<<dim3(256), 256, 0, stream>>>(Wq_first, Wq_last, Wqlhi, Wqllo, 65536);
  split4_kernel<<<dim3(256), 256, 0, stream>>>(Wk, Wkhi, Wklo, 65536);
  split4_kernel<<<dim3(256), 256, 0, stream>>>(Wv, Wvhi, Wvlo, 65536);
  split4_kernel<<<dim3(256), 256, 0, stream>>>(Wcomb, Wchi, Wclo, 65536);
  qg_kernel<<<dim3(2, 32), 256, 0, stream>>>(graph, Wq_graph, qg);

  // q = encL @ (Wq_first+Wq_last)^T + qg[b]    (encL dead afterwards)
  gemm_split_kernel<1, 1><<<dim3(4, 128, 1), 256, 0, stream>>>(
      encLhi, encLlo, Wqlhi, Wqllo, qhi, qlo, qg, 16384, 512, 512, 0, 0, 0);
  // k = encN @ Wk^T
  gemm_split_kernel<1, 0><<<dim3(4, 128, 1), 256, 0, stream>>>(
      encNhi, encNlo, Wkhi, Wklo, khi, klo, nullptr, 16384, 512, 512, 0, 0, 0);
  // v = encN @ Wv^T (row-major, verified epilogue)
  gemm_split_kernel<1, 0><<<dim3(4, 128, 1), 256, 0, stream>>>(
      encNhi, encNlo, Wvhi, Wvlo, vhi, vlo, nullptr, 16384, 512, 512, 0, 0, 0);
  // VT[b][h][d][n] via trivial transpose (replaces OUTMODE=2 suspect)
  vtrans_kernel<<<dim3(512), 256, 0, stream>>>(vhi, vlo, vThi, vTlo);

  attn_mfma_kernel<<<dim3(2048), 256, 0, stream>>>(
      qhi, qlo, khi, klo, vThi, vTlo, mask, athi, atlo);

  // mh = attn_out @ Wcomb^T + bcomb
  gemm_split_kernel<1, 2><<<dim3(4, 128, 1), 256, 0, stream>>>(
      athi, atlo, Wchi, Wclo, mhhi, mhlo, bcomb, 16384, 512, 512, 0, 0, 0);
  // s2 raw = mh[b] @ encN[b]^T -> fp32 into d_out (batched over b)
  gemm_split_kernel<0, 0><<<dim3(4, 4, 32), 256, 0, stream>>>(
      mhhi, mhlo, encNhi, encNlo, out, nullptr, nullptr, 512, 512, 512,
      262144, 262144, 262144);

  softmax2_kernel<<<dim3(4096), 256, 0, stream>>>(out, mask);
}

// Round 5
// 532.872 us; speedup vs baseline: 2.8023x; 1.1000x over previous
//
#include <hip/hip_runtime.h>
#include <hip/hip_bf16.h>
#include <stdint.h>
#include <math.h>

// Problem constants
#define B_  32
#define N_  512
#define G_  512
#define D_  512
#define H_  16
#define KD_ 32

using bf16x8 = __attribute__((ext_vector_type(8))) short;
using f32x4  = __attribute__((ext_vector_type(4))) float;
typedef unsigned short u16;

__device__ __forceinline__ u16 f2b(float x) {
  union { __hip_bfloat16 h; u16 u; } c;
  c.h = __float2bfloat16(x);
  return c.u;
}
__device__ __forceinline__ float b2f(u16 u) {
  union { float f; unsigned int i; } c;
  c.i = ((unsigned int)u) << 16;
  return c.f;
}

// async global->LDS, 16B per lane. LDS dest is wave-uniform base; HW adds lane*16.
__device__ __forceinline__ void async16(void* lds, const void* g) {
  __builtin_amdgcn_global_load_lds(
      (const __attribute__((address_space(1))) unsigned int*)(uintptr_t)g,
      (__attribute__((address_space(3))) unsigned int*)(uintptr_t)lds,
      16, 0, 0);
}

// ---------------------------------------------------------------------------
// mean partials fused with hi/lo split of encoded_nodes. grid (32,8), block 512.
__global__ __launch_bounds__(512) void mean_split_kernel(
    const float* __restrict__ enc, u16* __restrict__ hi, u16* __restrict__ lo,
    float* __restrict__ partial)
{
  const int b  = blockIdx.x;
  const int nc = blockIdx.y;       // 8 chunks of 64 n
  const int d  = threadIdx.x;      // 512
  const size_t base = ((size_t)b * N_ + (size_t)nc * 64) * D_ + d;
  float psum = 0.f;
  for (int i = 0; i < 64; ++i) {
    float v = enc[base + (size_t)i * D_];
    psum += v;
    u16 h = f2b(v);
    hi[base + (size_t)i * D_] = h;
    lo[base + (size_t)i * D_] = f2b(v - b2f(h));
  }
  partial[((size_t)b * 8 + nc) * D_ + d] = psum;
}

// graph[b][d] = sum(partial)/512. grid 32, block 512.
__global__ __launch_bounds__(512) void mean_final_kernel(
    const float* __restrict__ partial, float* __restrict__ graph)
{
  const int b = blockIdx.x, d = threadIdx.x;
  float s = 0.f;
  for (int c = 0; c < 8; ++c) s += partial[((size_t)b * 8 + c) * D_ + d];
  graph[b * D_ + d] = s * (1.0f / N_);
}

// generic fp32 -> (hi,lo) bf16 split, 4 elems/thread
__global__ void split4_kernel(const float* __restrict__ in,
                              u16* __restrict__ hi, u16* __restrict__ lo, int n4)
{
  int i = blockIdx.x * blockDim.x + threadIdx.x;
  if (i < n4) {
    float4 v = ((const float4*)in)[i];
    ushort4 h, l;
    h.x = f2b(v.x); l.x = f2b(v.x - b2f(h.x));
    h.y = f2b(v.y); l.y = f2b(v.y - b2f(h.y));
    h.z = f2b(v.z); l.z = f2b(v.z - b2f(h.z));
    h.w = f2b(v.w); l.w = f2b(v.w - b2f(h.w));
    ((ushort4*)hi)[i] = h;
    ((ushort4*)lo)[i] = l;
  }
}

// (a+b) -> hi/lo split (for Wq_first + Wq_last)
__global__ void wsum_split_kernel(const float* __restrict__ a, const float* __restrict__ b,
                                  u16* __restrict__ hi, u16* __restrict__ lo, int n4)
{
  int i = blockIdx.x * blockDim.x + threadIdx.x;
  if (i < n4) {
    float4 va = ((const float4*)a)[i];
    float4 vb = ((const float4*)b)[i];
    float x0 = va.x + vb.x, x1 = va.y + vb.y, x2 = va.z + vb.z, x3 = va.w + vb.w;
    ushort4 h, l;
    h.x = f2b(x0); l.x = f2b(x0 - b2f(h.x));
    h.y = f2b(x1); l.y = f2b(x1 - b2f(h.y));
    h.z = f2b(x2); l.z = f2b(x2 - b2f(h.z));
    h.w = f2b(x3); l.w = f2b(x3 - b2f(h.w));
    ((ushort4*)hi)[i] = h;
    ((ushort4*)lo)[i] = l;
  }
}

// qg[b][d] = dot(graph[b][:], Wq_graph[d][:])  (tiny, fp32). grid (2,32), block 256
__global__ __launch_bounds__(256) void qg_kernel(
    const float* __restrict__ graph, const float* __restrict__ Wq,
    float* __restrict__ qg)
{
  const int b  = blockIdx.y;
  const int dd = blockIdx.x * 256 + threadIdx.x;
  const float* g = graph + b * D_;
  const float* w = Wq + (size_t)dd * D_;
  float s = 0.f;
  for (int k = 0; k < D_; ++k) s += g[k] * w[k];
  qg[b * D_ + dd] = s;
}

// ---------------------------------------------------------------------------
// V transpose out of merged kv: VT[b][h][d][n] = kv[b*512+n][512 + h*32 + d].
// grid 512 = b*16+h, block 256.
__global__ __launch_bounds__(256) void vtrans_kernel(
    const u16* __restrict__ kvhi, const u16* __restrict__ kvlo,
    u16* __restrict__ vThi, u16* __restrict__ vTlo)
{
  const int b = blockIdx.x >> 4, h = blockIdx.x & 15;
  for (int d = 0; d < 32; ++d) {
#pragma unroll
    for (int c = 0; c < 2; ++c) {
      const int n = c * 256 + threadIdx.x;
      const size_t src = ((size_t)(b * 512 + n)) * 1024 + 512 + h * 32 + d;
      const size_t dst = (((size_t)b * 16 + h) * 32 + d) * 512 + n;
      vThi[dst] = kvhi[src];
      vTlo[dst] = kvlo[src];
    }
  }
}

// ---------------------------------------------------------------------------
// C[M,N] = A[M,K] @ B[N,K]^T with split-precision bf16 (hi+lo pairs), fp32 accum.
// acc += Alo*Bhi + Ahi*Blo + Ahi*Bhi   (lo*lo dropped, ~2^-18)
// OUTMODE: 0 = fp32 single out (batched via sC), 1 = hi/lo bf16 row-major
// BIASMODE: 0 none, 1 +bias[(r>>9)*512 + c] (qg broadcast), 2 +bias[c] (bcomb)
// 128x128 tile, BK=32, 4 waves (2x2), wave tile 64x64. m97 structure.
template<int OUTMODE, int BIASMODE>
__global__ __launch_bounds__(256) void gemm_split_kernel(
    const u16* __restrict__ Ahi, const u16* __restrict__ Alo,
    const u16* __restrict__ Bhi, const u16* __restrict__ Blo,
    void* __restrict__ Chi, void* __restrict__ Clo,
    const float* __restrict__ bias,
    int M, int N, int K, long sA, long sB, long sC)
{
  __shared__ __align__(16) u16 AhS[4096], AlS[4096], BhS[4096], BlS[4096];

  const int z = blockIdx.z;
  Ahi += (size_t)z * sA; Alo += (size_t)z * sA;
  Bhi += (size_t)z * sB; Blo += (size_t)z * sB;

  const int brow = blockIdx.y * 128;
  const int bcol = blockIdx.x * 128;
  const int tid  = threadIdx.x;
  const int wid  = tid >> 6;
  const int lane = tid & 63;
  const int wr = wid >> 1, wc = wid & 1;

  f32x4 acc[4][4] = {};

  const int c0   = wid * 2;
  const int srow = lane >> 2;        // 0..15
  const int skk  = (lane & 3) * 8;   // 0,8,16,24

  const size_t g0 = (size_t)(brow + c0 * 16      + srow) * K + skk;
  const size_t g1 = (size_t)(brow + c0 * 16 + 16 + srow) * K + skk;
  const size_t h0 = (size_t)(bcol + c0 * 16      + srow) * K + skk;
  const size_t h1 = (size_t)(bcol + c0 * 16 + 16 + srow) * K + skk;
  u16* lA0 = &AhS[c0 * 512]; u16* lA1 = &AhS[c0 * 512 + 512];
  u16* la0 = &AlS[c0 * 512]; u16* la1 = &AlS[c0 * 512 + 512];
  u16* lB0 = &BhS[c0 * 512]; u16* lB1 = &BhS[c0 * 512 + 512];
  u16* lb0 = &BlS[c0 * 512]; u16* lb1 = &BlS[c0 * 512 + 512];

  const int aoff = (wr * 64 + (lane & 15)) * 32 + (lane >> 4) * 8;
  const int boff = (wc * 64 + (lane & 15)) * 32 + (lane >> 4) * 8;

  for (int k0 = 0; k0 < K; k0 += 32) {
    async16(lA0, Ahi + g0 + k0);
    async16(lA1, Ahi + g1 + k0);
    async16(la0, Alo + g0 + k0);
    async16(la1, Alo + g1 + k0);
    async16(lB0, Bhi + h0 + k0);
    async16(lB1, Bhi + h1 + k0);
    async16(lb0, Blo + h0 + k0);
    async16(lb1, Blo + h1 + k0);
    __syncthreads();   // drains vmcnt(0) before barrier

    bf16x8 ah[4], al[4], bh[4], bl[4];
#pragma unroll
    for (int m = 0; m < 4; ++m) {
      ah[m] = *(const bf16x8*)&AhS[aoff + m * 512];
      al[m] = *(const bf16x8*)&AlS[aoff + m * 512];
    }
#pragma unroll
    for (int n = 0; n < 4; ++n) {
      bh[n] = *(const bf16x8*)&BhS[boff + n * 512];
      bl[n] = *(const bf16x8*)&BlS[boff + n * 512];
    }
#pragma unroll
    for (int m = 0; m < 4; ++m)
#pragma unroll
      for (int n = 0; n < 4; ++n) {
        f32x4 t = acc[m][n];
        t = __builtin_amdgcn_mfma_f32_16x16x32_bf16(al[m], bh[n], t, 0, 0, 0);
        t = __builtin_amdgcn_mfma_f32_16x16x32_bf16(ah[m], bl[n], t, 0, 0, 0);
        t = __builtin_amdgcn_mfma_f32_16x16x32_bf16(ah[m], bh[n], t, 0, 0, 0);
        acc[m][n] = t;
      }
    __syncthreads();   // protect LDS before next stage overwrites
  }

  // epilogue. C/D layout: col = lane&15, row = (lane>>4)*4 + reg
  const int r0 = brow + wr * 64 + (lane >> 4) * 4;
  const int cbase = bcol + wc * 64 + (lane & 15);
#pragma unroll
  for (int m = 0; m < 4; ++m) {
#pragma unroll
    for (int n = 0; n < 4; ++n) {
      const int c = cbase + n * 16;
#pragma unroll
      for (int j = 0; j < 4; ++j) {
        const int r = r0 + m * 16 + j;
        float v = acc[m][n][j];
        if (BIASMODE == 1) v += bias[(r >> 9) * 512 + c];
        if (BIASMODE == 2) v += bias[c];
        if (OUTMODE == 0) {
          ((float*)Chi)[(size_t)z * sC + (size_t)r * N + c] = v;
        } else {
          u16 h = f2b(v);
          ((u16*)Chi)[(size_t)r * N + c] = h;
          ((u16*)Clo)[(size_t)r * N + c] = f2b(v - b2f(h));
        }
      }
    }
  }
}

// ---------------------------------------------------------------------------
// Stage-1 attention v2. Two-pass softmax; pass A hi-only (shift-invariance makes
// approximate max exact-safe). Per-lane running max (one shfl reduce at end);
// row sums via P*ones MFMA; no __syncthreads (P buffer is per-wave, DS in-order
// per wave + lgkmcnt(0) suffices). O written in-place over Q (disjoint slices).
// K read from merged kv buffer (row stride 1024). grid 2048, block 256.
__global__ __launch_bounds__(256) void attn_mfma2_kernel(
    u16* __restrict__ Qhi, u16* __restrict__ Qlo,              // in: Q, out: O
    const u16* __restrict__ KVhi, const u16* __restrict__ KVlo, // [16384][1024]
    const u16* __restrict__ VThi, const u16* __restrict__ VTlo, // [b][h][32][512]
    const float* __restrict__ mask)
{
  __shared__ __align__(16) u16 Ph[4][32][56], Pl[4][32][56];  // 112B row stride

  const int tid = threadIdx.x, wid = tid >> 6, lane = tid & 63;
  const int id   = blockIdx.x;
  const int h    = id & 15;
  const int gblk = (id >> 4) & 3;
  const int b    = id >> 6;
  const int g0   = gblk * 128 + wid * 32;
  const int colq = lane & 15, rowg = lane >> 4;

  const size_t qb = ((size_t)b * G_ + g0) * D_ + h * KD_;
  const size_t kb = (size_t)b * N_ * 1024 + h * KD_;
  const size_t vb = (((size_t)b * H_ + h) * KD_) * (size_t)N_;
  const float* Mb = mask + ((size_t)b * G_ + g0) * N_;

  bf16x8 qh[2], ql[2];
  qh[0] = *(const bf16x8*)&Qhi[qb + (size_t)colq * D_ + rowg * 8];
  ql[0] = *(const bf16x8*)&Qlo[qb + (size_t)colq * D_ + rowg * 8];
  qh[1] = *(const bf16x8*)&Qhi[qb + (size_t)(16 + colq) * D_ + rowg * 8];
  ql[1] = *(const bf16x8*)&Qlo[qb + (size_t)(16 + colq) * D_ + rowg * 8];

  const float scale = 0.17677669529663687f;  // 1/sqrt(32)
  const f32x4 zf = {0.f, 0.f, 0.f, 0.f};
  const bf16x8 ones = {0x3F80, 0x3F80, 0x3F80, 0x3F80, 0x3F80, 0x3F80, 0x3F80, 0x3F80};

  // ---- pass A: approximate row maxima, hi-only QK^T, per-lane running max ----
  float mloc[2][4];
#pragma unroll
  for (int rf = 0; rf < 2; ++rf)
#pragma unroll
    for (int j = 0; j < 4; ++j) mloc[rf][j] = -3.0e38f;

  for (int n0 = 0; n0 < N_; n0 += 32) {
    bf16x8 kh0 = *(const bf16x8*)&KVhi[kb + (size_t)(n0 + colq) * 1024 + rowg * 8];
    bf16x8 kh1 = *(const bf16x8*)&KVhi[kb + (size_t)(n0 + 16 + colq) * 1024 + rowg * 8];
#pragma unroll
    for (int rf = 0; rf < 2; ++rf) {
      f32x4 t0 = __builtin_amdgcn_mfma_f32_16x16x32_bf16(qh[rf], kh0, zf, 0, 0, 0);
      f32x4 t1 = __builtin_amdgcn_mfma_f32_16x16x32_bf16(qh[rf], kh1, zf, 0, 0, 0);
#pragma unroll
      for (int j = 0; j < 4; ++j) {
        const int gg = rf * 16 + rowg * 4 + j;
        float v0 = t0[j] * scale + Mb[(size_t)gg * N_ + n0 + colq];
        float v1 = t1[j] * scale + Mb[(size_t)gg * N_ + n0 + 16 + colq];
        mloc[rf][j] = fmaxf(mloc[rf][j], fmaxf(v0, v1));
      }
    }
  }
  float mrow[2][4];
#pragma unroll
  for (int rf = 0; rf < 2; ++rf)
#pragma unroll
    for (int j = 0; j < 4; ++j) {
      float m = mloc[rf][j];
#pragma unroll
      for (int w = 1; w < 16; w <<= 1) m = fmaxf(m, __shfl_xor(m, w));
      mrow[rf][j] = m;
    }

  // ---- pass B: P = exp(s - m), P.V and P.1 accumulation ----
  f32x4 o[2][2] = {};
  f32x4 os[2] = {};

  for (int n0 = 0; n0 < N_; n0 += 32) {
    bf16x8 kh0 = *(const bf16x8*)&KVhi[kb + (size_t)(n0 + colq) * 1024 + rowg * 8];
    bf16x8 kl0 = *(const bf16x8*)&KVlo[kb + (size_t)(n0 + colq) * 1024 + rowg * 8];
    bf16x8 kh1 = *(const bf16x8*)&KVhi[kb + (size_t)(n0 + 16 + colq) * 1024 + rowg * 8];
    bf16x8 kl1 = *(const bf16x8*)&KVlo[kb + (size_t)(n0 + 16 + colq) * 1024 + rowg * 8];
    // V loads issued early: latency hides under QK^T + softmax VALU work
    bf16x8 vh0 = *(const bf16x8*)&VThi[vb + (size_t)colq * N_ + n0 + rowg * 8];
    bf16x8 vl0 = *(const bf16x8*)&VTlo[vb + (size_t)colq * N_ + n0 + rowg * 8];
    bf16x8 vh1 = *(const bf16x8*)&VThi[vb + (size_t)(16 + colq) * N_ + n0 + rowg * 8];
    bf16x8 vl1 = *(const bf16x8*)&VTlo[vb + (size_t)(16 + colq) * N_ + n0 + rowg * 8];

#pragma unroll
    for (int rf = 0; rf < 2; ++rf) {
      f32x4 t0 = __builtin_amdgcn_mfma_f32_16x16x32_bf16(ql[rf], kh0, zf, 0, 0, 0);
      t0 = __builtin_amdgcn_mfma_f32_16x16x32_bf16(qh[rf], kl0, t0, 0, 0, 0);
      t0 = __builtin_amdgcn_mfma_f32_16x16x32_bf16(qh[rf], kh0, t0, 0, 0, 0);
      f32x4 t1 = __builtin_amdgcn_mfma_f32_16x16x32_bf16(ql[rf], kh1, zf, 0, 0, 0);
      t1 = __builtin_amdgcn_mfma_f32_16x16x32_bf16(qh[rf], kl1, t1, 0, 0, 0);
      t1 = __builtin_amdgcn_mfma_f32_16x16x32_bf16(qh[rf], kh1, t1, 0, 0, 0);
#pragma unroll
      for (int j = 0; j < 4; ++j) {
        const int gg = rf * 16 + rowg * 4 + j;
        float v0 = t0[j] * scale + Mb[(size_t)gg * N_ + n0 + colq];
        float v1 = t1[j] * scale + Mb[(size_t)gg * N_ + n0 + 16 + colq];
        float p0 = __expf(v0 - mrow[rf][j]);
        float p1 = __expf(v1 - mrow[rf][j]);
        u16 h0 = f2b(p0), h1 = f2b(p1);
        Ph[wid][gg][colq]      = h0;
        Pl[wid][gg][colq]      = f2b(p0 - b2f(h0));
        Ph[wid][gg][16 + colq] = h1;
        Pl[wid][gg][16 + colq] = f2b(p1 - b2f(h1));
      }
    }
    // P buffer is per-wave: within-wave DS ordering + lgkmcnt drain suffice.
    asm volatile("s_waitcnt lgkmcnt(0)" ::: "memory");

    bf16x8 ph0 = *(const bf16x8*)&Ph[wid][colq][rowg * 8];
    bf16x8 pl0 = *(const bf16x8*)&Pl[wid][colq][rowg * 8];
    bf16x8 ph1 = *(const bf16x8*)&Ph[wid][16 + colq][rowg * 8];
    bf16x8 pl1 = *(const bf16x8*)&Pl[wid][16 + colq][rowg * 8];

    o[0][0] = __builtin_amdgcn_mfma_f32_16x16x32_bf16(pl0, vh0, o[0][0], 0, 0, 0);
    o[0][0] = __builtin_amdgcn_mfma_f32_16x16x32_bf16(ph0, vl0, o[0][0], 0, 0, 0);
    o[0][0] = __builtin_amdgcn_mfma_f32_16x16x32_bf16(ph0, vh0, o[0][0], 0, 0, 0);
    o[0][1] = __builtin_amdgcn_mfma_f32_16x16x32_bf16(pl0, vh1, o[0][1], 0, 0, 0);
    o[0][1] = __builtin_amdgcn_mfma_f32_16x16x32_bf16(ph0, vl1, o[0][1], 0, 0, 0);
    o[0][1] = __builtin_amdgcn_mfma_f32_16x16x32_bf16(ph0, vh1, o[0][1], 0, 0, 0);
    o[1][0] = __builtin_amdgcn_mfma_f32_16x16x32_bf16(pl1, vh0, o[1][0], 0, 0, 0);
    o[1][0] = __builtin_amdgcn_mfma_f32_16x16x32_bf16(ph1, vl0, o[1][0], 0, 0, 0);
    o[1][0] = __builtin_amdgcn_mfma_f32_16x16x32_bf16(ph1, vh0, o[1][0], 0, 0, 0);
    o[1][1] = __builtin_amdgcn_mfma_f32_16x16x32_bf16(pl1, vh1, o[1][1], 0, 0, 0);
    o[1][1] = __builtin_amdgcn_mfma_f32_16x16x32_bf16(ph1, vl1, o[1][1], 0, 0, 0);
    o[1][1] = __builtin_amdgcn_mfma_f32_16x16x32_bf16(ph1, vh1, o[1][1], 0, 0, 0);
    // row sums: P @ ones (hi + lo), accumulated across tiles
    os[0] = __builtin_amdgcn_mfma_f32_16x16x32_bf16(ph0, ones, os[0], 0, 0, 0);
    os[0] = __builtin_amdgcn_mfma_f32_16x16x32_bf16(pl0, ones, os[0], 0, 0, 0);
    os[1] = __builtin_amdgcn_mfma_f32_16x16x32_bf16(ph1, ones, os[1], 0, 0, 0);
    os[1] = __builtin_amdgcn_mfma_f32_16x16x32_bf16(pl1, ones, os[1], 0, 0, 0);
  }

#pragma unroll
  for (int rf = 0; rf < 2; ++rf)
#pragma unroll
    for (int j = 0; j < 4; ++j) {
      const float inv = 1.f / os[rf][j];
      const int gg = rf * 16 + rowg * 4 + j;
      float v0 = o[rf][0][j] * inv;
      float v1 = o[rf][1][j] * inv;
      u16 h0 = f2b(v0), h1 = f2b(v1);
      Qhi[qb + (size_t)gg * D_ + colq]      = h0;   // in-place O
      Qlo[qb + (size_t)gg * D_ + colq]      = f2b(v0 - b2f(h0));
      Qhi[qb + (size_t)gg * D_ + 16 + colq] = h1;
      Qlo[qb + (size_t)gg * D_ + 16 + colq] = f2b(v1 - b2f(h1));
    }
}

// ---------------------------------------------------------------------------
// Stage-2: s = 10*tanh(raw/sqrt(512)) + mask; softmax over n. In-place on d_out.
__global__ __launch_bounds__(256) void softmax2_kernel(
    float* __restrict__ S, const float* __restrict__ mask)
{
  const int row  = blockIdx.x * 4 + (threadIdx.x >> 6);
  const int lane = threadIdx.x & 63;
  float* r = S + (size_t)row * N_;
  const float* mk = mask + (size_t)row * N_;
  const float iscale = 0.04419417382415922f;  // 1/sqrt(512)

  float4 a  = *(const float4*)&r[lane * 8];
  float4 b4 = *(const float4*)&r[lane * 8 + 4];
  float4 ma = *(const float4*)&mk[lane * 8];
  float4 mb = *(const float4*)&mk[lane * 8 + 4];

  float v[8] = {a.x, a.y, a.z, a.w, b4.x, b4.y, b4.z, b4.w};
  float m[8] = {ma.x, ma.y, ma.z, ma.w, mb.x, mb.y, mb.z, mb.w};

#pragma unroll
  for (int i = 0; i < 8; ++i) {
    float x  = v[i] * iscale;
    float e2 = __expf(2.f * x);
    float t  = 1.f - 2.f / (e2 + 1.f);
    v[i] = 10.f * t + m[i];
  }
  float mx = v[0];
#pragma unroll
  for (int i = 1; i < 8; ++i) mx = fmaxf(mx, v[i]);
#pragma unroll
  for (int w = 1; w < 64; w <<= 1) mx = fmaxf(mx, __shfl_xor(mx, w));
  float sum = 0.f;
#pragma unroll
  for (int i = 0; i < 8; ++i) { v[i] = __expf(v[i] - mx); sum += v[i]; }
#pragma unroll
  for (int w = 1; w < 64; w <<= 1) sum += __shfl_xor(sum, w);
  const float inv = 1.f / sum;

  float4 oa = {v[0] * inv, v[1] * inv, v[2] * inv, v[3] * inv};
  float4 ob = {v[4] * inv, v[5] * inv, v[6] * inv, v[7] * inv};
  *(float4*)&r[lane * 8]     = oa;
  *(float4*)&r[lane * 8 + 4] = ob;
}

// ---------------------------------------------------------------------------
extern "C" void kernel_launch(void* const* d_in, const int* in_sizes, int n_in,
                              void* d_out, int out_size, void* d_ws, size_t ws_size,
                              hipStream_t stream)
{
  const float* enc_nodes = (const float*)d_in[0];
  const float* enc_last  = (const float*)d_in[1];
  const float* mask      = (const float*)d_in[2];
  const float* Wq_graph  = (const float*)d_in[3];
  const float* Wq_first  = (const float*)d_in[4];
  const float* Wq_last   = (const float*)d_in[5];
  const float* Wk        = (const float*)d_in[6];
  const float* Wv        = (const float*)d_in[7];
  const float* Wcomb     = (const float*)d_in[8];
  const float* bcomb     = (const float*)d_in[9];
  float* out = (float*)d_out;

  char* ws = (char*)d_ws;
  size_t off = 0;
  auto alloc = [&](size_t bytes) {
    void* p = ws + off;
    off += (bytes + 255) & ~(size_t)255;
    return p;
  };

  const size_t EL = (size_t)B_ * G_ * D_;  // 8388608
  u16* encNhi = (u16*)alloc(EL * 2);
  u16* encNlo = (u16*)alloc(EL * 2);
  u16* encLhi = (u16*)alloc(EL * 2);   // -> reused as VT hi after q GEMM
  u16* encLlo = (u16*)alloc(EL * 2);   // -> reused as VT lo
  u16* qhi    = (u16*)alloc(EL * 2);   // q -> attn output in-place -> mh GEMM input
  u16* qlo    = (u16*)alloc(EL * 2);
  u16* kvhi   = (u16*)alloc(EL * 4);   // merged [16384][1024] -> reused as mh hi
  u16* kvlo   = (u16*)alloc(EL * 4);   // -> reused as mh lo
  u16* Wqlhi  = (u16*)alloc((size_t)D_ * D_ * 2);
  u16* Wqllo  = (u16*)alloc((size_t)D_ * D_ * 2);
  u16* Wkvhi  = (u16*)alloc((size_t)D_ * D_ * 4);  // [1024][512]
  u16* Wkvlo  = (u16*)alloc((size_t)D_ * D_ * 4);
  u16* Wchi   = (u16*)alloc((size_t)D_ * D_ * 2);
  u16* Wclo   = (u16*)alloc((size_t)D_ * D_ * 2);
  float* partial = (float*)alloc((size_t)B_ * 8 * D_ * 4);
  float* graph   = (float*)alloc((size_t)B_ * D_ * 4);
  float* qg      = (float*)alloc((size_t)B_ * D_ * 4);
  u16* vThi = encLhi; u16* vTlo = encLlo;  // encL dead after q GEMM
  u16* athi = qhi;    u16* atlo = qlo;     // attention output in-place over q
  u16* mhhi = kvhi;   u16* mhlo = kvlo;    // kv dead after attention

  mean_split_kernel<<<dim3(32, 8), 512, 0, stream>>>(enc_nodes, encNhi, encNlo, partial);
  mean_final_kernel<<<dim3(32), 512, 0, stream>>>(partial, graph);
  split4_kernel<<<dim3(8192), 256, 0, stream>>>(enc_last, encLhi, encLlo, (int)(EL / 4));
  wsum_split_kernel<<<dim3(256), 256, 0, stream>>>(Wq_first, Wq_last, Wqlhi, Wqllo, 65536);
  split4_kernel<<<dim3(256), 256, 0, stream>>>(Wk, Wkvhi, Wkvlo, 65536);
  split4_kernel<<<dim3(256), 256, 0, stream>>>(Wv, Wkvhi + 262144, Wkvlo + 262144, 65536);
  split4_kernel<<<dim3(256), 256, 0, stream>>>(Wcomb, Wchi, Wclo, 65536);
  qg_kernel<<<dim3(2, 32), 256, 0, stream>>>(graph, Wq_graph, qg);

  // q = encL @ (Wq_first+Wq_last)^T + qg[b]    (encL dead afterwards)
  gemm_split_kernel<1, 1><<<dim3(4, 128, 1), 256, 0, stream>>>(
      encLhi, encLlo, Wqlhi, Wqllo, qhi, qlo, qg, 16384, 512, 512, 0, 0, 0);
  // kv = encN @ [Wk;Wv]^T  -> [16384][1024] (k cols 0-511, v cols 512-1023)
  gemm_split_kernel<1, 0><<<dim3(8, 128, 1), 256, 0, stream>>>(
      encNhi, encNlo, Wkvhi, Wkvlo, kvhi, kvlo, nullptr, 16384, 1024, 512, 0, 0, 0);
  // VT[b][h][d][n] from kv's v-half
  vtrans_kernel<<<dim3(512), 256, 0, stream>>>(kvhi, kvlo, vThi, vTlo);

  attn_mfma2_kernel<<<dim3(2048), 256, 0, stream>>>(
      qhi, qlo, kvhi, kvlo, vThi, vTlo, mask);

  // mh = attn_out @ Wcomb^T + bcomb   (kv dead -> mh into kv buffers)
  gemm_split_kernel<1, 2><<<dim3(4, 128, 1), 256, 0, stream>>>(
      athi, atlo, Wchi, Wclo, mhhi, mhlo, bcomb, 16384, 512, 512, 0, 0, 0);
  // s2 raw = mh[b] @ encN[b]^T -> fp32 into d_out (batched over b)
  gemm_split_kernel<0, 0><<<dim3(4, 4, 32), 256, 0, stream>>>(
      mhhi, mhlo, encNhi, encNlo, out, nullptr, nullptr, 512, 512, 512,
      262144, 262144, 262144);

  softmax2_kernel<<<dim3(4096), 256, 0, stream>>>(out, mask);
}

// Round 6
// 494.824 us; speedup vs baseline: 3.0178x; 1.0769x over previous
//
#include <hip/hip_runtime.h>
#include <hip/hip_bf16.h>
#include <stdint.h>
#include <math.h>

// Problem constants
#define B_  32
#define N_  512
#define G_  512
#define D_  512
#define H_  16
#define KD_ 32

using bf16x8 = __attribute__((ext_vector_type(8))) short;
using f32x4  = __attribute__((ext_vector_type(4))) float;
typedef unsigned short u16;

__device__ __forceinline__ u16 f2b(float x) {
  union { __hip_bfloat16 h; u16 u; } c;
  c.h = __float2bfloat16(x);
  return c.u;
}
__device__ __forceinline__ float b2f(u16 u) {
  union { float f; unsigned int i; } c;
  c.i = ((unsigned int)u) << 16;
  return c.f;
}

// async global->LDS, 16B per lane. LDS dest is wave-uniform base; HW adds lane*16.
__device__ __forceinline__ void async16(void* lds, const void* g) {
  __builtin_amdgcn_global_load_lds(
      (const __attribute__((address_space(1))) unsigned int*)(uintptr_t)g,
      (__attribute__((address_space(3))) unsigned int*)(uintptr_t)lds,
      16, 0, 0);
}

// ---------------------------------------------------------------------------
// mean partials fused with hi/lo split of encoded_nodes. grid (32,8), block 512.
__global__ __launch_bounds__(512) void mean_split_kernel(
    const float* __restrict__ enc, u16* __restrict__ hi, u16* __restrict__ lo,
    float* __restrict__ partial)
{
  const int b  = blockIdx.x;
  const int nc = blockIdx.y;       // 8 chunks of 64 n
  const int d  = threadIdx.x;      // 512
  const size_t base = ((size_t)b * N_ + (size_t)nc * 64) * D_ + d;
  float psum = 0.f;
  for (int i = 0; i < 64; ++i) {
    float v = enc[base + (size_t)i * D_];
    psum += v;
    u16 h = f2b(v);
    hi[base + (size_t)i * D_] = h;
    lo[base + (size_t)i * D_] = f2b(v - b2f(h));
  }
  partial[((size_t)b * 8 + nc) * D_ + d] = psum;
}

// graph[b][d] = sum(partial)/512. grid 32, block 512.
__global__ __launch_bounds__(512) void mean_final_kernel(
    const float* __restrict__ partial, float* __restrict__ graph)
{
  const int b = blockIdx.x, d = threadIdx.x;
  float s = 0.f;
  for (int c = 0; c < 8; ++c) s += partial[((size_t)b * 8 + c) * D_ + d];
  graph[b * D_ + d] = s * (1.0f / N_);
}

// generic fp32 -> (hi,lo) bf16 split, 4 elems/thread
__global__ void split4_kernel(const float* __restrict__ in,
                              u16* __restrict__ hi, u16* __restrict__ lo, int n4)
{
  int i = blockIdx.x * blockDim.x + threadIdx.x;
  if (i < n4) {
    float4 v = ((const float4*)in)[i];
    ushort4 h, l;
    h.x = f2b(v.x); l.x = f2b(v.x - b2f(h.x));
    h.y = f2b(v.y); l.y = f2b(v.y - b2f(h.y));
    h.z = f2b(v.z); l.z = f2b(v.z - b2f(h.z));
    h.w = f2b(v.w); l.w = f2b(v.w - b2f(h.w));
    ((ushort4*)hi)[i] = h;
    ((ushort4*)lo)[i] = l;
  }
}

// (a+b) -> hi/lo split (for Wq_first + Wq_last)
__global__ void wsum_split_kernel(const float* __restrict__ a, const float* __restrict__ b,
                                  u16* __restrict__ hi, u16* __restrict__ lo, int n4)
{
  int i = blockIdx.x * blockDim.x + threadIdx.x;
  if (i < n4) {
    float4 va = ((const float4*)a)[i];
    float4 vb = ((const float4*)b)[i];
    float x0 = va.x + vb.x, x1 = va.y + vb.y, x2 = va.z + vb.z, x3 = va.w + vb.w;
    ushort4 h, l;
    h.x = f2b(x0); l.x = f2b(x0 - b2f(h.x));
    h.y = f2b(x1); l.y = f2b(x1 - b2f(h.y));
    h.z = f2b(x2); l.z = f2b(x2 - b2f(h.z));
    h.w = f2b(x3); l.w = f2b(x3 - b2f(h.w));
    ((ushort4*)hi)[i] = h;
    ((ushort4*)lo)[i] = l;
  }
}

// qg[b][d] = dot(graph[b][:], Wq_graph[d][:])  (tiny, fp32). grid (2,32), block 256
__global__ __launch_bounds__(256) void qg_kernel(
    const float* __restrict__ graph, const float* __restrict__ Wq,
    float* __restrict__ qg)
{
  const int b  = blockIdx.y;
  const int dd = blockIdx.x * 256 + threadIdx.x;
  const float* g = graph + b * D_;
  const float* w = Wq + (size_t)dd * D_;
  float s = 0.f;
  for (int k = 0; k < D_; ++k) s += g[k] * w[k];
  qg[b * D_ + dd] = s;
}

// ---------------------------------------------------------------------------
// rowmax of mask per (b,g) row. grid 4096, block 256 (4 rows/block, 1 wave/row).
__global__ __launch_bounds__(256) void rowmax_kernel(
    const float* __restrict__ mask, float* __restrict__ rmx)
{
  const int row  = blockIdx.x * 4 + (threadIdx.x >> 6);
  const int lane = threadIdx.x & 63;
  const float* r = mask + (size_t)row * N_;
  float4 a  = *(const float4*)&r[lane * 8];
  float4 b4 = *(const float4*)&r[lane * 8 + 4];
  float m = fmaxf(fmaxf(fmaxf(a.x, a.y), fmaxf(a.z, a.w)),
                  fmaxf(fmaxf(b4.x, b4.y), fmaxf(b4.z, b4.w)));
#pragma unroll
  for (int w = 1; w < 64; w <<= 1) m = fmaxf(m, __shfl_xor(m, w));
  if (lane == 0) rmx[row] = m;
}

// max_n ||k_n||_2 per (b,h), from khi half of kv. grid 512, block 64 (1 wave).
__global__ __launch_bounds__(64) void kmax_kernel(
    const u16* __restrict__ kvhi, float* __restrict__ kmx)
{
  const int b = blockIdx.x >> 4, h = blockIdx.x & 15;
  const int lane = threadIdx.x;
  float mx = 0.f;
  for (int i = 0; i < 8; ++i) {
    const int n = i * 64 + lane;
    const unsigned int* p =
        (const unsigned int*)&kvhi[((size_t)b * 512 + n) * 1024 + h * 32];
    float s = 0.f;
#pragma unroll
    for (int w = 0; w < 16; ++w) {
      unsigned int u = p[w];
      float f0 = __uint_as_float(u << 16);
      float f1 = __uint_as_float(u & 0xffff0000u);
      s = fmaf(f0, f0, s);
      s = fmaf(f1, f1, s);
    }
    mx = fmaxf(mx, s);
  }
#pragma unroll
  for (int w = 1; w < 64; w <<= 1) mx = fmaxf(mx, __shfl_xor(mx, w));
  if (lane == 0) kmx[blockIdx.x] = sqrtf(mx) * 1.01f;  // covers dropped lo parts
}

// ---------------------------------------------------------------------------
// V transpose out of merged kv: VT[b][h][d][n] = kv[b*512+n][512 + h*32 + d].
// grid 512 = b*16+h, block 256.
__global__ __launch_bounds__(256) void vtrans_kernel(
    const u16* __restrict__ kvhi, const u16* __restrict__ kvlo,
    u16* __restrict__ vThi, u16* __restrict__ vTlo)
{
  const int b = blockIdx.x >> 4, h = blockIdx.x & 15;
  for (int d = 0; d < 32; ++d) {
#pragma unroll
    for (int c = 0; c < 2; ++c) {
      const int n = c * 256 + threadIdx.x;
      const size_t src = ((size_t)(b * 512 + n)) * 1024 + 512 + h * 32 + d;
      const size_t dst = (((size_t)b * 16 + h) * 32 + d) * 512 + n;
      vThi[dst] = kvhi[src];
      vTlo[dst] = kvlo[src];
    }
  }
}

// ---------------------------------------------------------------------------
// C[M,N] = A[M,K] @ B[N,K]^T with split-precision bf16 (hi+lo pairs), fp32 accum.
// acc += Alo*Bhi + Ahi*Blo + Ahi*Bhi   (lo*lo dropped, ~2^-18)
// OUTMODE: 0 = fp32 single out (batched via sC), 1 = hi/lo bf16 row-major
// BIASMODE: 0 none, 1 +bias[(r>>9)*512 + c] (qg broadcast), 2 +bias[c] (bcomb)
// 128x128 tile, BK=32, 4 waves (2x2), wave tile 64x64. m97 structure.
template<int OUTMODE, int BIASMODE>
__global__ __launch_bounds__(256) void gemm_split_kernel(
    const u16* __restrict__ Ahi, const u16* __restrict__ Alo,
    const u16* __restrict__ Bhi, const u16* __restrict__ Blo,
    void* __restrict__ Chi, void* __restrict__ Clo,
    const float* __restrict__ bias,
    int M, int N, int K, long sA, long sB, long sC)
{
  __shared__ __align__(16) u16 AhS[4096], AlS[4096], BhS[4096], BlS[4096];

  const int z = blockIdx.z;
  Ahi += (size_t)z * sA; Alo += (size_t)z * sA;
  Bhi += (size_t)z * sB; Blo += (size_t)z * sB;

  const int brow = blockIdx.y * 128;
  const int bcol = blockIdx.x * 128;
  const int tid  = threadIdx.x;
  const int wid  = tid >> 6;
  const int lane = tid & 63;
  const int wr = wid >> 1, wc = wid & 1;

  f32x4 acc[4][4] = {};

  const int c0   = wid * 2;
  const int srow = lane >> 2;        // 0..15
  const int skk  = (lane & 3) * 8;   // 0,8,16,24

  const size_t g0 = (size_t)(brow + c0 * 16      + srow) * K + skk;
  const size_t g1 = (size_t)(brow + c0 * 16 + 16 + srow) * K + skk;
  const size_t h0 = (size_t)(bcol + c0 * 16      + srow) * K + skk;
  const size_t h1 = (size_t)(bcol + c0 * 16 + 16 + srow) * K + skk;
  u16* lA0 = &AhS[c0 * 512]; u16* lA1 = &AhS[c0 * 512 + 512];
  u16* la0 = &AlS[c0 * 512]; u16* la1 = &AlS[c0 * 512 + 512];
  u16* lB0 = &BhS[c0 * 512]; u16* lB1 = &BhS[c0 * 512 + 512];
  u16* lb0 = &BlS[c0 * 512]; u16* lb1 = &BlS[c0 * 512 + 512];

  const int aoff = (wr * 64 + (lane & 15)) * 32 + (lane >> 4) * 8;
  const int boff = (wc * 64 + (lane & 15)) * 32 + (lane >> 4) * 8;

  for (int k0 = 0; k0 < K; k0 += 32) {
    async16(lA0, Ahi + g0 + k0);
    async16(lA1, Ahi + g1 + k0);
    async16(la0, Alo + g0 + k0);
    async16(la1, Alo + g1 + k0);
    async16(lB0, Bhi + h0 + k0);
    async16(lB1, Bhi + h1 + k0);
    async16(lb0, Blo + h0 + k0);
    async16(lb1, Blo + h1 + k0);
    __syncthreads();   // drains vmcnt(0) before barrier

    bf16x8 ah[4], al[4], bh[4], bl[4];
#pragma unroll
    for (int m = 0; m < 4; ++m) {
      ah[m] = *(const bf16x8*)&AhS[aoff + m * 512];
      al[m] = *(const bf16x8*)&AlS[aoff + m * 512];
    }
#pragma unroll
    for (int n = 0; n < 4; ++n) {
      bh[n] = *(const bf16x8*)&BhS[boff + n * 512];
      bl[n] = *(const bf16x8*)&BlS[boff + n * 512];
    }
#pragma unroll
    for (int m = 0; m < 4; ++m)
#pragma unroll
      for (int n = 0; n < 4; ++n) {
        f32x4 t = acc[m][n];
        t = __builtin_amdgcn_mfma_f32_16x16x32_bf16(al[m], bh[n], t, 0, 0, 0);
        t = __builtin_amdgcn_mfma_f32_16x16x32_bf16(ah[m], bl[n], t, 0, 0, 0);
        t = __builtin_amdgcn_mfma_f32_16x16x32_bf16(ah[m], bh[n], t, 0, 0, 0);
        acc[m][n] = t;
      }
    __syncthreads();   // protect LDS before next stage overwrites
  }

  // epilogue. C/D layout: col = lane&15, row = (lane>>4)*4 + reg
  const int r0 = brow + wr * 64 + (lane >> 4) * 4;
  const int cbase = bcol + wc * 64 + (lane & 15);
#pragma unroll
  for (int m = 0; m < 4; ++m) {
#pragma unroll
    for (int n = 0; n < 4; ++n) {
      const int c = cbase + n * 16;
#pragma unroll
      for (int j = 0; j < 4; ++j) {
        const int r = r0 + m * 16 + j;
        float v = acc[m][n][j];
        if (BIASMODE == 1) v += bias[(r >> 9) * 512 + c];
        if (BIASMODE == 2) v += bias[c];
        if (OUTMODE == 0) {
          ((float*)Chi)[(size_t)z * sC + (size_t)r * N + c] = v;
        } else {
          u16 h = f2b(v);
          ((u16*)Chi)[(size_t)r * N + c] = h;
          ((u16*)Clo)[(size_t)r * N + c] = f2b(v - b2f(h));
        }
      }
    }
  }
}

// ---------------------------------------------------------------------------
// Stage-1 attention v3: SINGLE pass. Shift m_hat >= true row max computed from
// analytic bound: scale*||q_g||*Kmax(b,h) + rowmax(mask). Softmax with any
// shift >= max is exact after normalization (we divide by the computed sum);
// bound gap is small so no underflow. P hi/lo conversion via v_cvt_pk_bf16_f32.
// Row sums via P@ones MFMA. O in-place over Q. grid 2048, block 256.
__global__ __launch_bounds__(256) void attn_mfma3_kernel(
    u16* __restrict__ Qhi, u16* __restrict__ Qlo,               // in: Q, out: O
    const u16* __restrict__ KVhi, const u16* __restrict__ KVlo, // [16384][1024]
    const u16* __restrict__ VThi, const u16* __restrict__ VTlo, // [b][h][32][512]
    const float* __restrict__ mask,
    const float* __restrict__ rowmaxb,   // [16384]
    const float* __restrict__ kmaxb)     // [512]
{
  __shared__ __align__(16) u16 Ph[4][32][56], Pl[4][32][56];  // 112B row stride

  const int tid = threadIdx.x, wid = tid >> 6, lane = tid & 63;
  const int id   = blockIdx.x;
  const int h    = id & 15;
  const int gblk = (id >> 4) & 3;
  const int b    = id >> 6;
  const int g0   = gblk * 128 + wid * 32;
  const int colq = lane & 15, rowg = lane >> 4;

  const size_t qb = ((size_t)b * G_ + g0) * D_ + h * KD_;
  const size_t kb = (size_t)b * N_ * 1024 + h * KD_;
  const size_t vb = (((size_t)b * H_ + h) * KD_) * (size_t)N_;
  const float* Mb = mask + ((size_t)b * G_ + g0) * N_;

  bf16x8 qh[2], ql[2];
  qh[0] = *(const bf16x8*)&Qhi[qb + (size_t)colq * D_ + rowg * 8];
  ql[0] = *(const bf16x8*)&Qlo[qb + (size_t)colq * D_ + rowg * 8];
  qh[1] = *(const bf16x8*)&Qhi[qb + (size_t)(16 + colq) * D_ + rowg * 8];
  ql[1] = *(const bf16x8*)&Qlo[qb + (size_t)(16 + colq) * D_ + rowg * 8];

  const float scale = 0.17677669529663687f;  // 1/sqrt(32)
  const f32x4 zf = {0.f, 0.f, 0.f, 0.f};
  const bf16x8 ones = {0x3F80, 0x3F80, 0x3F80, 0x3F80, 0x3F80, 0x3F80, 0x3F80, 0x3F80};

  // ---- prologue: per-row shift m_hat (upper bound of row max) ----
  const float km = kmaxb[b * 16 + h];
  float nq2[2];
#pragma unroll
  for (int rf = 0; rf < 2; ++rf) {
    float s = 0.f;
    const unsigned int* qw = (const unsigned int*)&qh[rf];
#pragma unroll
    for (int w = 0; w < 4; ++w) {
      unsigned int u = qw[w];
      float f0 = __uint_as_float(u << 16);
      float f1 = __uint_as_float(u & 0xffff0000u);
      s = fmaf(f0, f0, s);
      s = fmaf(f1, f1, s);
    }
    // sum over the 4 rowg lanes holding this q-row's other dims
    s += __shfl_xor(s, 16);
    s += __shfl_xor(s, 32);
    nq2[rf] = s;
  }
  float mrow[2][4];
#pragma unroll
  for (int rf = 0; rf < 2; ++rf)
#pragma unroll
    for (int j = 0; j < 4; ++j) {
      const int r16 = rowg * 4 + j;   // row within fragment, lives at lane r16
      float nq = sqrtf(__shfl(nq2[rf], r16)) * 1.01f;  // covers dropped lo
      mrow[rf][j] = scale * nq * km + rowmaxb[(size_t)b * G_ + g0 + rf * 16 + r16];
    }

  // ---- single pass: P = exp(s - m_hat), P.V and P.1 accumulation ----
  f32x4 o[2][2] = {};
  f32x4 os[2] = {};

  for (int n0 = 0; n0 < N_; n0 += 32) {
    bf16x8 kh0 = *(const bf16x8*)&KVhi[kb + (size_t)(n0 + colq) * 1024 + rowg * 8];
    bf16x8 kl0 = *(const bf16x8*)&KVlo[kb + (size_t)(n0 + colq) * 1024 + rowg * 8];
    bf16x8 kh1 = *(const bf16x8*)&KVhi[kb + (size_t)(n0 + 16 + colq) * 1024 + rowg * 8];
    bf16x8 kl1 = *(const bf16x8*)&KVlo[kb + (size_t)(n0 + 16 + colq) * 1024 + rowg * 8];
    // V loads issued early: latency hides under QK^T + softmax VALU work
    bf16x8 vh0 = *(const bf16x8*)&VThi[vb + (size_t)colq * N_ + n0 + rowg * 8];
    bf16x8 vl0 = *(const bf16x8*)&VTlo[vb + (size_t)colq * N_ + n0 + rowg * 8];
    bf16x8 vh1 = *(const bf16x8*)&VThi[vb + (size_t)(16 + colq) * N_ + n0 + rowg * 8];
    bf16x8 vl1 = *(const bf16x8*)&VTlo[vb + (size_t)(16 + colq) * N_ + n0 + rowg * 8];

#pragma unroll
    for (int rf = 0; rf < 2; ++rf) {
      f32x4 t0 = __builtin_amdgcn_mfma_f32_16x16x32_bf16(ql[rf], kh0, zf, 0, 0, 0);
      t0 = __builtin_amdgcn_mfma_f32_16x16x32_bf16(qh[rf], kl0, t0, 0, 0, 0);
      t0 = __builtin_amdgcn_mfma_f32_16x16x32_bf16(qh[rf], kh0, t0, 0, 0, 0);
      f32x4 t1 = __builtin_amdgcn_mfma_f32_16x16x32_bf16(ql[rf], kh1, zf, 0, 0, 0);
      t1 = __builtin_amdgcn_mfma_f32_16x16x32_bf16(qh[rf], kl1, t1, 0, 0, 0);
      t1 = __builtin_amdgcn_mfma_f32_16x16x32_bf16(qh[rf], kh1, t1, 0, 0, 0);
#pragma unroll
      for (int j = 0; j < 4; ++j) {
        const int gg = rf * 16 + rowg * 4 + j;
        float m0 = Mb[(size_t)gg * N_ + n0 + colq];
        float m1 = Mb[(size_t)gg * N_ + n0 + 16 + colq];
        float p0 = __expf(fmaf(t0[j], scale, m0 - mrow[rf][j]));
        float p1 = __expf(fmaf(t1[j], scale, m1 - mrow[rf][j]));
        unsigned int uh, ul;
        asm("v_cvt_pk_bf16_f32 %0, %1, %2" : "=v"(uh) : "v"(p0), "v"(p1));
        float h0f = __uint_as_float(uh << 16);
        float h1f = __uint_as_float(uh & 0xffff0000u);
        float l0 = p0 - h0f, l1 = p1 - h1f;
        asm("v_cvt_pk_bf16_f32 %0, %1, %2" : "=v"(ul) : "v"(l0), "v"(l1));
        Ph[wid][gg][colq]      = (u16)uh;
        Ph[wid][gg][16 + colq] = (u16)(uh >> 16);
        Pl[wid][gg][colq]      = (u16)ul;
        Pl[wid][gg][16 + colq] = (u16)(ul >> 16);
      }
    }
    // P buffer is per-wave: within-wave DS ordering + lgkmcnt drain suffice.
    asm volatile("s_waitcnt lgkmcnt(0)" ::: "memory");

    bf16x8 ph0 = *(const bf16x8*)&Ph[wid][colq][rowg * 8];
    bf16x8 pl0 = *(const bf16x8*)&Pl[wid][colq][rowg * 8];
    bf16x8 ph1 = *(const bf16x8*)&Ph[wid][16 + colq][rowg * 8];
    bf16x8 pl1 = *(const bf16x8*)&Pl[wid][16 + colq][rowg * 8];

    o[0][0] = __builtin_amdgcn_mfma_f32_16x16x32_bf16(pl0, vh0, o[0][0], 0, 0, 0);
    o[0][0] = __builtin_amdgcn_mfma_f32_16x16x32_bf16(ph0, vl0, o[0][0], 0, 0, 0);
    o[0][0] = __builtin_amdgcn_mfma_f32_16x16x32_bf16(ph0, vh0, o[0][0], 0, 0, 0);
    o[0][1] = __builtin_amdgcn_mfma_f32_16x16x32_bf16(pl0, vh1, o[0][1], 0, 0, 0);
    o[0][1] = __builtin_amdgcn_mfma_f32_16x16x32_bf16(ph0, vl1, o[0][1], 0, 0, 0);
    o[0][1] = __builtin_amdgcn_mfma_f32_16x16x32_bf16(ph0, vh1, o[0][1], 0, 0, 0);
    o[1][0] = __builtin_amdgcn_mfma_f32_16x16x32_bf16(pl1, vh0, o[1][0], 0, 0, 0);
    o[1][0] = __builtin_amdgcn_mfma_f32_16x16x32_bf16(ph1, vl0, o[1][0], 0, 0, 0);
    o[1][0] = __builtin_amdgcn_mfma_f32_16x16x32_bf16(ph1, vh0, o[1][0], 0, 0, 0);
    o[1][1] = __builtin_amdgcn_mfma_f32_16x16x32_bf16(pl1, vh1, o[1][1], 0, 0, 0);
    o[1][1] = __builtin_amdgcn_mfma_f32_16x16x32_bf16(ph1, vl1, o[1][1], 0, 0, 0);
    o[1][1] = __builtin_amdgcn_mfma_f32_16x16x32_bf16(ph1, vh1, o[1][1], 0, 0, 0);
    // row sums: P @ ones (hi + lo), accumulated across tiles
    os[0] = __builtin_amdgcn_mfma_f32_16x16x32_bf16(ph0, ones, os[0], 0, 0, 0);
    os[0] = __builtin_amdgcn_mfma_f32_16x16x32_bf16(pl0, ones, os[0], 0, 0, 0);
    os[1] = __builtin_amdgcn_mfma_f32_16x16x32_bf16(ph1, ones, os[1], 0, 0, 0);
    os[1] = __builtin_amdgcn_mfma_f32_16x16x32_bf16(pl1, ones, os[1], 0, 0, 0);
  }

#pragma unroll
  for (int rf = 0; rf < 2; ++rf)
#pragma unroll
    for (int j = 0; j < 4; ++j) {
      const float inv = 1.f / os[rf][j];
      const int gg = rf * 16 + rowg * 4 + j;
      float v0 = o[rf][0][j] * inv;
      float v1 = o[rf][1][j] * inv;
      u16 h0 = f2b(v0), h1 = f2b(v1);
      Qhi[qb + (size_t)gg * D_ + colq]      = h0;   // in-place O
      Qlo[qb + (size_t)gg * D_ + colq]      = f2b(v0 - b2f(h0));
      Qhi[qb + (size_t)gg * D_ + 16 + colq] = h1;
      Qlo[qb + (size_t)gg * D_ + 16 + colq] = f2b(v1 - b2f(h1));
    }
}

// ---------------------------------------------------------------------------
// Stage-2: s = 10*tanh(raw/sqrt(512)) + mask; softmax over n. In-place on d_out.
__global__ __launch_bounds__(256) void softmax2_kernel(
    float* __restrict__ S, const float* __restrict__ mask)
{
  const int row  = blockIdx.x * 4 + (threadIdx.x >> 6);
  const int lane = threadIdx.x & 63;
  float* r = S + (size_t)row * N_;
  const float* mk = mask + (size_t)row * N_;
  const float iscale = 0.04419417382415922f;  // 1/sqrt(512)

  float4 a  = *(const float4*)&r[lane * 8];
  float4 b4 = *(const float4*)&r[lane * 8 + 4];
  float4 ma = *(const float4*)&mk[lane * 8];
  float4 mb = *(const float4*)&mk[lane * 8 + 4];

  float v[8] = {a.x, a.y, a.z, a.w, b4.x, b4.y, b4.z, b4.w};
  float m[8] = {ma.x, ma.y, ma.z, ma.w, mb.x, mb.y, mb.z, mb.w};

#pragma unroll
  for (int i = 0; i < 8; ++i) {
    float x  = v[i] * iscale;
    float e2 = __expf(2.f * x);
    float t  = 1.f - 2.f / (e2 + 1.f);
    v[i] = 10.f * t + m[i];
  }
  float mx = v[0];
#pragma unroll
  for (int i = 1; i < 8; ++i) mx = fmaxf(mx, v[i]);
#pragma unroll
  for (int w = 1; w < 64; w <<= 1) mx = fmaxf(mx, __shfl_xor(mx, w));
  float sum = 0.f;
#pragma unroll
  for (int i = 0; i < 8; ++i) { v[i] = __expf(v[i] - mx); sum += v[i]; }
#pragma unroll
  for (int w = 1; w < 64; w <<= 1) sum += __shfl_xor(sum, w);
  const float inv = 1.f / sum;

  float4 oa = {v[0] * inv, v[1] * inv, v[2] * inv, v[3] * inv};
  float4 ob = {v[4] * inv, v[5] * inv, v[6] * inv, v[7] * inv};
  *(float4*)&r[lane * 8]     = oa;
  *(float4*)&r[lane * 8 + 4] = ob;
}

// ---------------------------------------------------------------------------
extern "C" void kernel_launch(void* const* d_in, const int* in_sizes, int n_in,
                              void* d_out, int out_size, void* d_ws, size_t ws_size,
                              hipStream_t stream)
{
  const float* enc_nodes = (const float*)d_in[0];
  const float* enc_last  = (const float*)d_in[1];
  const float* mask      = (const float*)d_in[2];
  const float* Wq_graph  = (const float*)d_in[3];
  const float* Wq_first  = (const float*)d_in[4];
  const float* Wq_last   = (const float*)d_in[5];
  const float* Wk        = (const float*)d_in[6];
  const float* Wv        = (const float*)d_in[7];
  const float* Wcomb     = (const float*)d_in[8];
  const float* bcomb     = (const float*)d_in[9];
  float* out = (float*)d_out;

  char* ws = (char*)d_ws;
  size_t off = 0;
  auto alloc = [&](size_t bytes) {
    void* p = ws + off;
    off += (bytes + 255) & ~(size_t)255;
    return p;
  };

  const size_t EL = (size_t)B_ * G_ * D_;  // 8388608
  u16* encNhi = (u16*)alloc(EL * 2);
  u16* encNlo = (u16*)alloc(EL * 2);
  u16* encLhi = (u16*)alloc(EL * 2);   // -> reused as VT hi after q GEMM
  u16* encLlo = (u16*)alloc(EL * 2);   // -> reused as VT lo
  u16* qhi    = (u16*)alloc(EL * 2);   // q -> attn output in-place -> mh GEMM input
  u16* qlo    = (u16*)alloc(EL * 2);
  u16* kvhi   = (u16*)alloc(EL * 4);   // merged [16384][1024] -> reused as mh hi
  u16* kvlo   = (u16*)alloc(EL * 4);   // -> reused as mh lo
  u16* Wqlhi  = (u16*)alloc((size_t)D_ * D_ * 2);
  u16* Wqllo  = (u16*)alloc((size_t)D_ * D_ * 2);
  u16* Wkvhi  = (u16*)alloc((size_t)D_ * D_ * 4);  // [1024][512]
  u16* Wkvlo  = (u16*)alloc((size_t)D_ * D_ * 4);
  u16* Wchi   = (u16*)alloc((size_t)D_ * D_ * 2);
  u16* Wclo   = (u16*)alloc((size_t)D_ * D_ * 2);
  float* partial = (float*)alloc((size_t)B_ * 8 * D_ * 4);
  float* graph   = (float*)alloc((size_t)B_ * D_ * 4);
  float* qg      = (float*)alloc((size_t)B_ * D_ * 4);
  float* rowmaxb = (float*)alloc((size_t)B_ * G_ * 4);
  float* kmaxb   = (float*)alloc((size_t)B_ * H_ * 4);
  u16* vThi = encLhi; u16* vTlo = encLlo;  // encL dead after q GEMM
  u16* athi = qhi;    u16* atlo = qlo;     // attention output in-place over q
  u16* mhhi = kvhi;   u16* mhlo = kvlo;    // kv dead after attention

  mean_split_kernel<<<dim3(32, 8), 512, 0, stream>>>(enc_nodes, encNhi, encNlo, partial);
  mean_final_kernel<<<dim3(32), 512, 0, stream>>>(partial, graph);
  split4_kernel<<<dim3(8192), 256, 0, stream>>>(enc_last, encLhi, encLlo, (int)(EL / 4));
  wsum_split_kernel<<<dim3(256), 256, 0, stream>>>(Wq_first, Wq_last, Wqlhi, Wqllo, 65536);
  split4_kernel<<<dim3(256), 256, 0, stream>>>(Wk, Wkvhi, Wkvlo, 65536);
  split4_kernel<<<dim3(256), 256, 0, stream>>>(Wv, Wkvhi + 262144, Wkvlo + 262144, 65536);
  split4_kernel<<<dim3(256), 256, 0, stream>>>(Wcomb, Wchi, Wclo, 65536);
  qg_kernel<<<dim3(2, 32), 256, 0, stream>>>(graph, Wq_graph, qg);
  rowmax_kernel<<<dim3(4096), 256, 0, stream>>>(mask, rowmaxb);

  // q = encL @ (Wq_first+Wq_last)^T + qg[b]    (encL dead afterwards)
  gemm_split_kernel<1, 1><<<dim3(4, 128, 1), 256, 0, stream>>>(
      encLhi, encLlo, Wqlhi, Wqllo, qhi, qlo, qg, 16384, 512, 512, 0, 0, 0);
  // kv = encN @ [Wk;Wv]^T  -> [16384][1024] (k cols 0-511, v cols 512-1023)
  gemm_split_kernel<1, 0><<<dim3(8, 128, 1), 256, 0, stream>>>(
      encNhi, encNlo, Wkvhi, Wkvlo, kvhi, kvlo, nullptr, 16384, 1024, 512, 0, 0, 0);
  // VT[b][h][d][n] from kv's v-half; per-(b,h) K norm bound
  vtrans_kernel<<<dim3(512), 256, 0, stream>>>(kvhi, kvlo, vThi, vTlo);
  kmax_kernel<<<dim3(512), 64, 0, stream>>>(kvhi, kmaxb);

  attn_mfma3_kernel<<<dim3(2048), 256, 0, stream>>>(
      qhi, qlo, kvhi, kvlo, vThi, vTlo, mask, rowmaxb, kmaxb);

  // mh = attn_out @ Wcomb^T + bcomb   (kv dead -> mh into kv buffers)
  gemm_split_kernel<1, 2><<<dim3(4, 128, 1), 256, 0, stream>>>(
      athi, atlo, Wchi, Wclo, mhhi, mhlo, bcomb, 16384, 512, 512, 0, 0, 0);
  // s2 raw = mh[b] @ encN[b]^T -> fp32 into d_out (batched over b)
  gemm_split_kernel<0, 0><<<dim3(4, 4, 32), 256, 0, stream>>>(
      mhhi, mhlo, encNhi, encNlo, out, nullptr, nullptr, 512, 512, 512,
      262144, 262144, 262144);

  softmax2_kernel<<<dim3(4096), 256, 0, stream>>>(out, mask);
}

// Round 7
// 462.957 us; speedup vs baseline: 3.2255x; 1.0688x over previous
//
#include <hip/hip_runtime.h>
#include <hip/hip_bf16.h>
#include <stdint.h>
#include <math.h>

// Problem constants
#define B_  32
#define N_  512
#define G_  512
#define D_  512
#define H_  16
#define KD_ 32

using bf16x8 = __attribute__((ext_vector_type(8))) short;
using f32x4  = __attribute__((ext_vector_type(4))) float;
typedef unsigned short u16;

__device__ __forceinline__ u16 f2b(float x) {
  union { __hip_bfloat16 h; u16 u; } c;
  c.h = __float2bfloat16(x);
  return c.u;
}
__device__ __forceinline__ float b2f(u16 u) {
  union { float f; unsigned int i; } c;
  c.i = ((unsigned int)u) << 16;
  return c.f;
}

// async global->LDS, 16B per lane. LDS dest is wave-uniform base; HW adds lane*16.
__device__ __forceinline__ void async16(void* lds, const void* g) {
  __builtin_amdgcn_global_load_lds(
      (const __attribute__((address_space(1))) unsigned int*)(uintptr_t)g,
      (__attribute__((address_space(3))) unsigned int*)(uintptr_t)lds,
      16, 0, 0);
}

// ---------------------------------------------------------------------------
// mean partials fused with hi/lo split of encoded_nodes. grid (32,8), block 512.
__global__ __launch_bounds__(512) void mean_split_kernel(
    const float* __restrict__ enc, u16* __restrict__ hi, u16* __restrict__ lo,
    float* __restrict__ partial)
{
  const int b  = blockIdx.x;
  const int nc = blockIdx.y;       // 8 chunks of 64 n
  const int d  = threadIdx.x;      // 512
  const size_t base = ((size_t)b * N_ + (size_t)nc * 64) * D_ + d;
  float psum = 0.f;
  for (int i = 0; i < 64; ++i) {
    float v = enc[base + (size_t)i * D_];
    psum += v;
    u16 h = f2b(v);
    hi[base + (size_t)i * D_] = h;
    lo[base + (size_t)i * D_] = f2b(v - b2f(h));
  }
  partial[((size_t)b * 8 + nc) * D_ + d] = psum;
}

// graph[b][d] = sum(partial)/512. grid 32, block 512.
__global__ __launch_bounds__(512) void mean_final_kernel(
    const float* __restrict__ partial, float* __restrict__ graph)
{
  const int b = blockIdx.x, d = threadIdx.x;
  float s = 0.f;
  for (int c = 0; c < 8; ++c) s += partial[((size_t)b * 8 + c) * D_ + d];
  graph[b * D_ + d] = s * (1.0f / N_);
}

// generic fp32 -> (hi,lo) bf16 split, 4 elems/thread
__global__ void split4_kernel(const float* __restrict__ in,
                              u16* __restrict__ hi, u16* __restrict__ lo, int n4)
{
  int i = blockIdx.x * blockDim.x + threadIdx.x;
  if (i < n4) {
    float4 v = ((const float4*)in)[i];
    ushort4 h, l;
    h.x = f2b(v.x); l.x = f2b(v.x - b2f(h.x));
    h.y = f2b(v.y); l.y = f2b(v.y - b2f(h.y));
    h.z = f2b(v.z); l.z = f2b(v.z - b2f(h.z));
    h.w = f2b(v.w); l.w = f2b(v.w - b2f(h.w));
    ((ushort4*)hi)[i] = h;
    ((ushort4*)lo)[i] = l;
  }
}

// (a+b) -> hi/lo split (for Wq_first + Wq_last)
__global__ void wsum_split_kernel(const float* __restrict__ a, const float* __restrict__ b,
                                  u16* __restrict__ hi, u16* __restrict__ lo, int n4)
{
  int i = blockIdx.x * blockDim.x + threadIdx.x;
  if (i < n4) {
    float4 va = ((const float4*)a)[i];
    float4 vb = ((const float4*)b)[i];
    float x0 = va.x + vb.x, x1 = va.y + vb.y, x2 = va.z + vb.z, x3 = va.w + vb.w;
    ushort4 h, l;
    h.x = f2b(x0); l.x = f2b(x0 - b2f(h.x));
    h.y = f2b(x1); l.y = f2b(x1 - b2f(h.y));
    h.z = f2b(x2); l.z = f2b(x2 - b2f(h.z));
    h.w = f2b(x3); l.w = f2b(x3 - b2f(h.w));
    ((ushort4*)hi)[i] = h;
    ((ushort4*)lo)[i] = l;
  }
}

// qg[b][d] = dot(graph[b][:], Wq_graph[d][:])  (tiny, fp32). grid (2,32), block 256
__global__ __launch_bounds__(256) void qg_kernel(
    const float* __restrict__ graph, const float* __restrict__ Wq,
    float* __restrict__ qg)
{
  const int b  = blockIdx.y;
  const int dd = blockIdx.x * 256 + threadIdx.x;
  const float* g = graph + b * D_;
  const float* w = Wq + (size_t)dd * D_;
  float s = 0.f;
  for (int k = 0; k < D_; ++k) s += g[k] * w[k];
  qg[b * D_ + dd] = s;
}

// ---------------------------------------------------------------------------
// rowmax of mask per (b,g) row. grid 4096, block 256 (4 rows/block, 1 wave/row).
__global__ __launch_bounds__(256) void rowmax_kernel(
    const float* __restrict__ mask, float* __restrict__ rmx)
{
  const int row  = blockIdx.x * 4 + (threadIdx.x >> 6);
  const int lane = threadIdx.x & 63;
  const float* r = mask + (size_t)row * N_;
  float4 a  = *(const float4*)&r[lane * 8];
  float4 b4 = *(const float4*)&r[lane * 8 + 4];
  float m = fmaxf(fmaxf(fmaxf(a.x, a.y), fmaxf(a.z, a.w)),
                  fmaxf(fmaxf(b4.x, b4.y), fmaxf(b4.z, b4.w)));
#pragma unroll
  for (int w = 1; w < 64; w <<= 1) m = fmaxf(m, __shfl_xor(m, w));
  if (lane == 0) rmx[row] = m;
}

// max_n ||k_n||_2 per (b,h), from khi [16384][512]. grid 512, block 64 (1 wave).
__global__ __launch_bounds__(64) void kmax_kernel(
    const u16* __restrict__ khi, float* __restrict__ kmx)
{
  const int b = blockIdx.x >> 4, h = blockIdx.x & 15;
  const int lane = threadIdx.x;
  float mx = 0.f;
  for (int i = 0; i < 8; ++i) {
    const int n = i * 64 + lane;
    const unsigned int* p =
        (const unsigned int*)&khi[((size_t)b * 512 + n) * 512 + h * 32];
    float s = 0.f;
#pragma unroll
    for (int w = 0; w < 16; ++w) {
      unsigned int u = p[w];
      float f0 = __uint_as_float(u << 16);
      float f1 = __uint_as_float(u & 0xffff0000u);
      s = fmaf(f0, f0, s);
      s = fmaf(f1, f1, s);
    }
    mx = fmaxf(mx, s);
  }
#pragma unroll
  for (int w = 1; w < 64; w <<= 1) mx = fmaxf(mx, __shfl_xor(mx, w));
  if (lane == 0) kmx[blockIdx.x] = sqrtf(mx) * 1.01f;  // covers dropped lo parts
}

// ---------------------------------------------------------------------------
// C[M,N] = A[M,K] @ B[N,K]^T with split-precision bf16 (hi+lo pairs), fp32 accum.
// acc += Alo*Bhi + Ahi*Blo + Ahi*Bhi   (lo*lo dropped, ~2^-18)
// OUTMODE: 0 = fp32 single out (batched via sC), 1 = hi/lo bf16 row-major,
//          3 = kv fused: c<512 -> K row-major [r][c] in Chi/Clo;
//              c>=512 -> VT[b][h][d][n] scatter into Dhi/Dlo
// BIASMODE: 0 none, 1 +bias[(r>>9)*512 + c] (qg broadcast), 2 +bias[c] (bcomb)
// 128x128 tile, BK=32, 4 waves (2x2), wave tile 64x64. m97 structure.
template<int OUTMODE, int BIASMODE>
__global__ __launch_bounds__(256) void gemm_split_kernel(
    const u16* __restrict__ Ahi, const u16* __restrict__ Alo,
    const u16* __restrict__ Bhi, const u16* __restrict__ Blo,
    void* __restrict__ Chi, void* __restrict__ Clo,
    void* __restrict__ Dhi, void* __restrict__ Dlo,
    const float* __restrict__ bias,
    int M, int N, int K, long sA, long sB, long sC)
{
  __shared__ __align__(16) u16 AhS[4096], AlS[4096], BhS[4096], BlS[4096];

  const int z = blockIdx.z;
  Ahi += (size_t)z * sA; Alo += (size_t)z * sA;
  Bhi += (size_t)z * sB; Blo += (size_t)z * sB;

  const int brow = blockIdx.y * 128;
  const int bcol = blockIdx.x * 128;
  const int tid  = threadIdx.x;
  const int wid  = tid >> 6;
  const int lane = tid & 63;
  const int wr = wid >> 1, wc = wid & 1;

  f32x4 acc[4][4] = {};

  const int c0   = wid * 2;
  const int srow = lane >> 2;        // 0..15
  const int skk  = (lane & 3) * 8;   // 0,8,16,24

  const size_t g0 = (size_t)(brow + c0 * 16      + srow) * K + skk;
  const size_t g1 = (size_t)(brow + c0 * 16 + 16 + srow) * K + skk;
  const size_t h0 = (size_t)(bcol + c0 * 16      + srow) * K + skk;
  const size_t h1 = (size_t)(bcol + c0 * 16 + 16 + srow) * K + skk;
  u16* lA0 = &AhS[c0 * 512]; u16* lA1 = &AhS[c0 * 512 + 512];
  u16* la0 = &AlS[c0 * 512]; u16* la1 = &AlS[c0 * 512 + 512];
  u16* lB0 = &BhS[c0 * 512]; u16* lB1 = &BhS[c0 * 512 + 512];
  u16* lb0 = &BlS[c0 * 512]; u16* lb1 = &BlS[c0 * 512 + 512];

  const int aoff = (wr * 64 + (lane & 15)) * 32 + (lane >> 4) * 8;
  const int boff = (wc * 64 + (lane & 15)) * 32 + (lane >> 4) * 8;

  for (int k0 = 0; k0 < K; k0 += 32) {
    async16(lA0, Ahi + g0 + k0);
    async16(lA1, Ahi + g1 + k0);
    async16(la0, Alo + g0 + k0);
    async16(la1, Alo + g1 + k0);
    async16(lB0, Bhi + h0 + k0);
    async16(lB1, Bhi + h1 + k0);
    async16(lb0, Blo + h0 + k0);
    async16(lb1, Blo + h1 + k0);
    __syncthreads();   // drains vmcnt(0) before barrier

    bf16x8 ah[4], al[4], bh[4], bl[4];
#pragma unroll
    for (int m = 0; m < 4; ++m) {
      ah[m] = *(const bf16x8*)&AhS[aoff + m * 512];
      al[m] = *(const bf16x8*)&AlS[aoff + m * 512];
    }
#pragma unroll
    for (int n = 0; n < 4; ++n) {
      bh[n] = *(const bf16x8*)&BhS[boff + n * 512];
      bl[n] = *(const bf16x8*)&BlS[boff + n * 512];
    }
#pragma unroll
    for (int m = 0; m < 4; ++m)
#pragma unroll
      for (int n = 0; n < 4; ++n) {
        f32x4 t = acc[m][n];
        t = __builtin_amdgcn_mfma_f32_16x16x32_bf16(al[m], bh[n], t, 0, 0, 0);
        t = __builtin_amdgcn_mfma_f32_16x16x32_bf16(ah[m], bl[n], t, 0, 0, 0);
        t = __builtin_amdgcn_mfma_f32_16x16x32_bf16(ah[m], bh[n], t, 0, 0, 0);
        acc[m][n] = t;
      }
    __syncthreads();   // protect LDS before next stage overwrites
  }

  // epilogue. C/D layout: col = lane&15, row = (lane>>4)*4 + reg
  const int r0 = brow + wr * 64 + (lane >> 4) * 4;
  const int cbase = bcol + wc * 64 + (lane & 15);
#pragma unroll
  for (int m = 0; m < 4; ++m) {
#pragma unroll
    for (int n = 0; n < 4; ++n) {
      const int c = cbase + n * 16;
#pragma unroll
      for (int j = 0; j < 4; ++j) {
        const int r = r0 + m * 16 + j;
        float v = acc[m][n][j];
        if (BIASMODE == 1) v += bias[(r >> 9) * 512 + c];
        if (BIASMODE == 2) v += bias[c];
        if (OUTMODE == 0) {
          ((float*)Chi)[(size_t)z * sC + (size_t)r * N + c] = v;
        } else if (OUTMODE == 1) {
          u16 h = f2b(v);
          ((u16*)Chi)[(size_t)r * N + c] = h;
          ((u16*)Clo)[(size_t)r * N + c] = f2b(v - b2f(h));
        } else {  // OUTMODE == 3
          u16 hv = f2b(v);
          u16 lv = f2b(v - b2f(hv));
          if (c < 512) {
            ((u16*)Chi)[(size_t)r * 512 + c] = hv;
            ((u16*)Clo)[(size_t)r * 512 + c] = lv;
          } else {
            const int bb = r >> 9, nn = r & 511, hh = (c >> 5) & 15, dd = c & 31;
            const size_t idx = (((size_t)bb * 16 + hh) * 32 + dd) * 512 + nn;
            ((u16*)Dhi)[idx] = hv;
            ((u16*)Dlo)[idx] = lv;
          }
        }
      }
    }
  }
}

// ---------------------------------------------------------------------------
// Stage-1 attention v4: single pass (analytic shift m_hat, exact after
// normalization) + 2-stage software pipeline with double-buffered P LDS.
// Body t: issue K/V/mask(t+1) loads -> lgkm+sched_barrier -> PV(t) from
// buf[t&1] -> QK(t+1) -> softmax(t+1) -> write buf[(t+1)&1]. No barriers
// (P slices are per-wave). O in-place over Q. grid 2048, block 256.
__global__ __launch_bounds__(256) void attn_mfma4_kernel(
    u16* __restrict__ Qhi, u16* __restrict__ Qlo,               // in: Q, out: O
    const u16* __restrict__ Khi, const u16* __restrict__ Klo,   // [16384][512]
    const u16* __restrict__ VThi, const u16* __restrict__ VTlo, // [b][h][32][512]
    const float* __restrict__ mask,
    const float* __restrict__ rowmaxb,   // [16384]
    const float* __restrict__ kmaxb)     // [512]
{
  // stride 40 u16 = 80B: 16B-aligned rows, 2-way banks on b128 reads. 40KB total.
  __shared__ __align__(16) u16 Ph[2][4][32][40], Pl[2][4][32][40];

  const int tid = threadIdx.x, wid = tid >> 6, lane = tid & 63;
  const int id   = blockIdx.x;
  const int h    = id & 15;
  const int gblk = (id >> 4) & 3;
  const int b    = id >> 6;
  const int g0   = gblk * 128 + wid * 32;
  const int colq = lane & 15, rowg = lane >> 4;

  const size_t qb = ((size_t)b * G_ + g0) * D_ + h * KD_;
  const size_t kb = ((size_t)b * N_) * D_ + h * KD_;
  const size_t vb = (((size_t)b * H_ + h) * KD_) * (size_t)N_;
  const float* Mb = mask + ((size_t)b * G_ + g0) * N_;

  bf16x8 qh[2], ql[2];
  qh[0] = *(const bf16x8*)&Qhi[qb + (size_t)colq * D_ + rowg * 8];
  ql[0] = *(const bf16x8*)&Qlo[qb + (size_t)colq * D_ + rowg * 8];
  qh[1] = *(const bf16x8*)&Qhi[qb + (size_t)(16 + colq) * D_ + rowg * 8];
  ql[1] = *(const bf16x8*)&Qlo[qb + (size_t)(16 + colq) * D_ + rowg * 8];

  const float scale = 0.17677669529663687f;  // 1/sqrt(32)
  const f32x4 zf = {0.f, 0.f, 0.f, 0.f};
  const bf16x8 ones = {0x3F80, 0x3F80, 0x3F80, 0x3F80, 0x3F80, 0x3F80, 0x3F80, 0x3F80};

  // pipeline register sets (statically indexed under full unroll)
  bf16x8 kh0[2], kl0[2], kh1[2], kl1[2];
  bf16x8 vh0[2], vl0[2], vh1[2], vl1[2];
  float  mm0[2][4], mm1[2][4];    // mask - m_hat for the tile being softmaxed

#define LOADK(s, n0_)                                                          \
  kh0[s] = *(const bf16x8*)&Khi[kb + (size_t)((n0_) + colq) * D_ + rowg * 8];  \
  kl0[s] = *(const bf16x8*)&Klo[kb + (size_t)((n0_) + colq) * D_ + rowg * 8];  \
  kh1[s] = *(const bf16x8*)&Khi[kb + (size_t)((n0_) + 16 + colq) * D_ + rowg * 8]; \
  kl1[s] = *(const bf16x8*)&Klo[kb + (size_t)((n0_) + 16 + colq) * D_ + rowg * 8];

#define LOADV(s, n0_)                                                          \
  vh0[s] = *(const bf16x8*)&VThi[vb + (size_t)colq * N_ + (n0_) + rowg * 8];   \
  vl0[s] = *(const bf16x8*)&VTlo[vb + (size_t)colq * N_ + (n0_) + rowg * 8];   \
  vh1[s] = *(const bf16x8*)&VThi[vb + (size_t)(16 + colq) * N_ + (n0_) + rowg * 8]; \
  vl1[s] = *(const bf16x8*)&VTlo[vb + (size_t)(16 + colq) * N_ + (n0_) + rowg * 8];

#define LOADM(n0_)                                                             \
  _Pragma("unroll") for (int rf = 0; rf < 2; ++rf)                             \
  _Pragma("unroll") for (int j = 0; j < 4; ++j) {                              \
    const int gg = rf * 16 + rowg * 4 + j;                                     \
    mm0[rf][j] = Mb[(size_t)gg * N_ + (n0_) + colq] - mrow[rf][j];             \
    mm1[rf][j] = Mb[(size_t)gg * N_ + (n0_) + 16 + colq] - mrow[rf][j];        \
  }

#define QKSM(s, bb)                                                            \
  _Pragma("unroll") for (int rf = 0; rf < 2; ++rf) {                           \
    f32x4 t0 = __builtin_amdgcn_mfma_f32_16x16x32_bf16(ql[rf], kh0[s], zf, 0, 0, 0); \
    t0 = __builtin_amdgcn_mfma_f32_16x16x32_bf16(qh[rf], kl0[s], t0, 0, 0, 0); \
    t0 = __builtin_amdgcn_mfma_f32_16x16x32_bf16(qh[rf], kh0[s], t0, 0, 0, 0); \
    f32x4 t1 = __builtin_amdgcn_mfma_f32_16x16x32_bf16(ql[rf], kh1[s], zf, 0, 0, 0); \
    t1 = __builtin_amdgcn_mfma_f32_16x16x32_bf16(qh[rf], kl1[s], t1, 0, 0, 0); \
    t1 = __builtin_amdgcn_mfma_f32_16x16x32_bf16(qh[rf], kh1[s], t1, 0, 0, 0); \
    _Pragma("unroll") for (int j = 0; j < 4; ++j) {                            \
      const int gg = rf * 16 + rowg * 4 + j;                                   \
      float p0 = __expf(fmaf(t0[j], scale, mm0[rf][j]));                       \
      float p1 = __expf(fmaf(t1[j], scale, mm1[rf][j]));                       \
      unsigned int uh_, ul_;                                                   \
      asm("v_cvt_pk_bf16_f32 %0, %1, %2" : "=v"(uh_) : "v"(p0), "v"(p1));      \
      float h0f = __uint_as_float(uh_ << 16);                                  \
      float h1f = __uint_as_float(uh_ & 0xffff0000u);                          \
      float l0_ = p0 - h0f, l1_ = p1 - h1f;                                    \
      asm("v_cvt_pk_bf16_f32 %0, %1, %2" : "=v"(ul_) : "v"(l0_), "v"(l1_));    \
      Ph[bb][wid][gg][colq]      = (u16)uh_;                                   \
      Ph[bb][wid][gg][16 + colq] = (u16)(uh_ >> 16);                           \
      Pl[bb][wid][gg][colq]      = (u16)ul_;                                   \
      Pl[bb][wid][gg][16 + colq] = (u16)(ul_ >> 16);                           \
    }                                                                          \
  }

#define PVACC(s, bb) {                                                         \
    bf16x8 ph0 = *(const bf16x8*)&Ph[bb][wid][colq][rowg * 8];                 \
    bf16x8 pl0 = *(const bf16x8*)&Pl[bb][wid][colq][rowg * 8];                 \
    bf16x8 ph1 = *(const bf16x8*)&Ph[bb][wid][16 + colq][rowg * 8];            \
    bf16x8 pl1 = *(const bf16x8*)&Pl[bb][wid][16 + colq][rowg * 8];            \
    o[0][0] = __builtin_amdgcn_mfma_f32_16x16x32_bf16(pl0, vh0[s], o[0][0], 0, 0, 0); \
    o[0][0] = __builtin_amdgcn_mfma_f32_16x16x32_bf16(ph0, vl0[s], o[0][0], 0, 0, 0); \
    o[0][0] = __builtin_amdgcn_mfma_f32_16x16x32_bf16(ph0, vh0[s], o[0][0], 0, 0, 0); \
    o[0][1] = __builtin_amdgcn_mfma_f32_16x16x32_bf16(pl0, vh1[s], o[0][1], 0, 0, 0); \
    o[0][1] = __builtin_amdgcn_mfma_f32_16x16x32_bf16(ph0, vl1[s], o[0][1], 0, 0, 0); \
    o[0][1] = __builtin_amdgcn_mfma_f32_16x16x32_bf16(ph0, vh1[s], o[0][1], 0, 0, 0); \
    o[1][0] = __builtin_amdgcn_mfma_f32_16x16x32_bf16(pl1, vh0[s], o[1][0], 0, 0, 0); \
    o[1][0] = __builtin_amdgcn_mfma_f32_16x16x32_bf16(ph1, vl0[s], o[1][0], 0, 0, 0); \
    o[1][0] = __builtin_amdgcn_mfma_f32_16x16x32_bf16(ph1, vh0[s], o[1][0], 0, 0, 0); \
    o[1][1] = __builtin_amdgcn_mfma_f32_16x16x32_bf16(pl1, vh1[s], o[1][1], 0, 0, 0); \
    o[1][1] = __builtin_amdgcn_mfma_f32_16x16x32_bf16(ph1, vl1[s], o[1][1], 0, 0, 0); \
    o[1][1] = __builtin_amdgcn_mfma_f32_16x16x32_bf16(ph1, vh1[s], o[1][1], 0, 0, 0); \
    os[0] = __builtin_amdgcn_mfma_f32_16x16x32_bf16(ph0, ones, os[0], 0, 0, 0); \
    os[0] = __builtin_amdgcn_mfma_f32_16x16x32_bf16(pl0, ones, os[0], 0, 0, 0); \
    os[1] = __builtin_amdgcn_mfma_f32_16x16x32_bf16(ph1, ones, os[1], 0, 0, 0); \
    os[1] = __builtin_amdgcn_mfma_f32_16x16x32_bf16(pl1, ones, os[1], 0, 0, 0); \
  }

  // ---- prologue: issue tile-0 loads, compute m_hat while they fly ----
  LOADK(0, 0)
  LOADV(0, 0)

  const float km = kmaxb[b * 16 + h];
  float nq2[2];
#pragma unroll
  for (int rf = 0; rf < 2; ++rf) {
    float s = 0.f;
    const unsigned int* qw = (const unsigned int*)&qh[rf];
#pragma unroll
    for (int w = 0; w < 4; ++w) {
      unsigned int u = qw[w];
      float f0 = __uint_as_float(u << 16);
      float f1 = __uint_as_float(u & 0xffff0000u);
      s = fmaf(f0, f0, s);
      s = fmaf(f1, f1, s);
    }
    s += __shfl_xor(s, 16);
    s += __shfl_xor(s, 32);
    nq2[rf] = s;
  }
  float mrow[2][4];
#pragma unroll
  for (int rf = 0; rf < 2; ++rf)
#pragma unroll
    for (int j = 0; j < 4; ++j) {
      const int r16 = rowg * 4 + j;
      float nq = sqrtf(__shfl(nq2[rf], r16)) * 1.01f;
      mrow[rf][j] = scale * nq * km + rowmaxb[(size_t)b * G_ + g0 + rf * 16 + r16];
    }

  LOADM(0)
  QKSM(0, 0)          // tile 0 -> buf 0

  f32x4 o[2][2] = {};
  f32x4 os[2] = {};

  // ---- pipelined main loop (fully unrolled; all indices static) ----
#pragma unroll
  for (int t = 0; t < 16; ++t) {
    const int cur = t & 1, nxt = cur ^ 1;
    if (t < 15) {
      LOADK(nxt, (t + 1) * 32)
      LOADV(nxt, (t + 1) * 32)
      LOADM((t + 1) * 32)
    }
    asm volatile("s_waitcnt lgkmcnt(0)" ::: "memory");
    __builtin_amdgcn_sched_barrier(0);
    PVACC(cur, cur)
    if (t < 15) {
      QKSM(nxt, nxt)
    }
  }

#undef LOADK
#undef LOADV
#undef LOADM
#undef QKSM
#undef PVACC

#pragma unroll
  for (int rf = 0; rf < 2; ++rf)
#pragma unroll
    for (int j = 0; j < 4; ++j) {
      const float inv = 1.f / os[rf][j];
      const int gg = rf * 16 + rowg * 4 + j;
      float v0 = o[rf][0][j] * inv;
      float v1 = o[rf][1][j] * inv;
      u16 h0 = f2b(v0), h1 = f2b(v1);
      Qhi[qb + (size_t)gg * D_ + colq]      = h0;   // in-place O
      Qlo[qb + (size_t)gg * D_ + colq]      = f2b(v0 - b2f(h0));
      Qhi[qb + (size_t)gg * D_ + 16 + colq] = h1;
      Qlo[qb + (size_t)gg * D_ + 16 + colq] = f2b(v1 - b2f(h1));
    }
}

// ---------------------------------------------------------------------------
// Stage-2: s = 10*tanh(raw/sqrt(512)) + mask; softmax over n. In-place on d_out.
__global__ __launch_bounds__(256) void softmax2_kernel(
    float* __restrict__ S, const float* __restrict__ mask)
{
  const int row  = blockIdx.x * 4 + (threadIdx.x >> 6);
  const int lane = threadIdx.x & 63;
  float* r = S + (size_t)row * N_;
  const float* mk = mask + (size_t)row * N_;
  const float iscale = 0.04419417382415922f;  // 1/sqrt(512)

  float4 a  = *(const float4*)&r[lane * 8];
  float4 b4 = *(const float4*)&r[lane * 8 + 4];
  float4 ma = *(const float4*)&mk[lane * 8];
  float4 mb = *(const float4*)&mk[lane * 8 + 4];

  float v[8] = {a.x, a.y, a.z, a.w, b4.x, b4.y, b4.z, b4.w};
  float m[8] = {ma.x, ma.y, ma.z, ma.w, mb.x, mb.y, mb.z, mb.w};

#pragma unroll
  for (int i = 0; i < 8; ++i) {
    float x  = v[i] * iscale;
    float e2 = __expf(2.f * x);
    float t  = 1.f - 2.f / (e2 + 1.f);
    v[i] = 10.f * t + m[i];
  }
  float mx = v[0];
#pragma unroll
  for (int i = 1; i < 8; ++i) mx = fmaxf(mx, v[i]);
#pragma unroll
  for (int w = 1; w < 64; w <<= 1) mx = fmaxf(mx, __shfl_xor(mx, w));
  float sum = 0.f;
#pragma unroll
  for (int i = 0; i < 8; ++i) { v[i] = __expf(v[i] - mx); sum += v[i]; }
#pragma unroll
  for (int w = 1; w < 64; w <<= 1) sum += __shfl_xor(sum, w);
  const float inv = 1.f / sum;

  float4 oa = {v[0] * inv, v[1] * inv, v[2] * inv, v[3] * inv};
  float4 ob = {v[4] * inv, v[5] * inv, v[6] * inv, v[7] * inv};
  *(float4*)&r[lane * 8]     = oa;
  *(float4*)&r[lane * 8 + 4] = ob;
}

// ---------------------------------------------------------------------------
extern "C" void kernel_launch(void* const* d_in, const int* in_sizes, int n_in,
                              void* d_out, int out_size, void* d_ws, size_t ws_size,
                              hipStream_t stream)
{
  const float* enc_nodes = (const float*)d_in[0];
  const float* enc_last  = (const float*)d_in[1];
  const float* mask      = (const float*)d_in[2];
  const float* Wq_graph  = (const float*)d_in[3];
  const float* Wq_first  = (const float*)d_in[4];
  const float* Wq_last   = (const float*)d_in[5];
  const float* Wk        = (const float*)d_in[6];
  const float* Wv        = (const float*)d_in[7];
  const float* Wcomb     = (const float*)d_in[8];
  const float* bcomb     = (const float*)d_in[9];
  float* out = (float*)d_out;

  char* ws = (char*)d_ws;
  size_t off = 0;
  auto alloc = [&](size_t bytes) {
    void* p = ws + off;
    off += (bytes + 255) & ~(size_t)255;
    return p;
  };

  const size_t EL = (size_t)B_ * G_ * D_;  // 8388608
  u16* encNhi = (u16*)alloc(EL * 2);
  u16* encNlo = (u16*)alloc(EL * 2);
  u16* encLhi = (u16*)alloc(EL * 2);   // -> reused as VT hi after q GEMM
  u16* encLlo = (u16*)alloc(EL * 2);   // -> reused as VT lo
  u16* qhi    = (u16*)alloc(EL * 2);   // q -> attn output in-place -> mh GEMM input
  u16* qlo    = (u16*)alloc(EL * 2);
  u16* khi    = (u16*)alloc(EL * 2);   // K [16384][512] -> reused as mh hi
  u16* klo    = (u16*)alloc(EL * 2);   // -> reused as mh lo
  u16* Wqlhi  = (u16*)alloc((size_t)D_ * D_ * 2);
  u16* Wqllo  = (u16*)alloc((size_t)D_ * D_ * 2);
  u16* Wkvhi  = (u16*)alloc((size_t)D_ * D_ * 4);  // [1024][512]
  u16* Wkvlo  = (u16*)alloc((size_t)D_ * D_ * 4);
  u16* Wchi   = (u16*)alloc((size_t)D_ * D_ * 2);
  u16* Wclo   = (u16*)alloc((size_t)D_ * D_ * 2);
  float* partial = (float*)alloc((size_t)B_ * 8 * D_ * 4);
  float* graph   = (float*)alloc((size_t)B_ * D_ * 4);
  float* qg      = (float*)alloc((size_t)B_ * D_ * 4);
  float* rowmaxb = (float*)alloc((size_t)B_ * G_ * 4);
  float* kmaxb   = (float*)alloc((size_t)B_ * H_ * 4);
  u16* vThi = encLhi; u16* vTlo = encLlo;  // encL dead after q GEMM
  u16* athi = qhi;    u16* atlo = qlo;     // attention output in-place over q
  u16* mhhi = khi;    u16* mhlo = klo;     // k dead after attention

  mean_split_kernel<<<dim3(32, 8), 512, 0, stream>>>(enc_nodes, encNhi, encNlo, partial);
  mean_final_kernel<<<dim3(32), 512, 0, stream>>>(partial, graph);
  split4_kernel<<<dim3(8192), 256, 0, stream>>>(enc_last, encLhi, encLlo, (int)(EL / 4));
  wsum_split_kernel<<<dim3(256), 256, 0, stream>>>(Wq_first, Wq_last, Wqlhi, Wqllo, 65536);
  split4_kernel<<<dim3(256), 256, 0, stream>>>(Wk, Wkvhi, Wkvlo, 65536);
  split4_kernel<<<dim3(256), 256, 0, stream>>>(Wv, Wkvhi + 262144, Wkvlo + 262144, 65536);
  split4_kernel<<<dim3(256), 256, 0, stream>>>(Wcomb, Wchi, Wclo, 65536);
  qg_kernel<<<dim3(2, 32), 256, 0, stream>>>(graph, Wq_graph, qg);
  rowmax_kernel<<<dim3(4096), 256, 0, stream>>>(mask, rowmaxb);

  // q = encL @ (Wq_first+Wq_last)^T + qg[b]    (encL dead afterwards)
  gemm_split_kernel<1, 1><<<dim3(4, 128, 1), 256, 0, stream>>>(
      encLhi, encLlo, Wqlhi, Wqllo, qhi, qlo, nullptr, nullptr, qg,
      16384, 512, 512, 0, 0, 0);
  // kv = encN @ [Wk;Wv]^T : K half row-major into khi/klo, V half direct to VT
  gemm_split_kernel<3, 0><<<dim3(8, 128, 1), 256, 0, stream>>>(
      encNhi, encNlo, Wkvhi, Wkvlo, khi, klo, vThi, vTlo, nullptr,
      16384, 1024, 512, 0, 0, 0);
  // per-(b,h) K norm bound
  kmax_kernel<<<dim3(512), 64, 0, stream>>>(khi, kmaxb);

  attn_mfma4_kernel<<<dim3(2048), 256, 0, stream>>>(
      qhi, qlo, khi, klo, vThi, vTlo, mask, rowmaxb, kmaxb);

  // mh = attn_out @ Wcomb^T + bcomb   (k dead -> mh into k buffers)
  gemm_split_kernel<1, 2><<<dim3(4, 128, 1), 256, 0, stream>>>(
      athi, atlo, Wchi, Wclo, mhhi, mhlo, nullptr, nullptr, bcomb,
      16384, 512, 512, 0, 0, 0);
  // s2 raw = mh[b] @ encN[b]^T -> fp32 into d_out (batched over b)
  gemm_split_kernel<0, 0><<<dim3(4, 4, 32), 256, 0, stream>>>(
      mhhi, mhlo, encNhi, encNlo, out, nullptr, nullptr, nullptr, nullptr,
      512, 512, 512, 262144, 262144, 262144);

  softmax2_kernel<<<dim3(4096), 256, 0, stream>>>(out, mask);
}